// Round 14
// baseline (4377.677 us; speedup 1.0000x reference)
//
#include <hip/hip_runtime.h>
#include <hip/hip_bf16.h>

// ShiftReduceCompressor: persistent kernel, 1 block/row (B=64), 1024 threads,
// 32-iteration scan in-kernel. Encoder fp32, sampling tail fp64, exact
// partitionable JAX threefry. Fused tail.
//
// Round 14 = R13 (best 4126us; coalesced weight tiles in d_ws) + JG=2 x T=4
// on Wqkv/W1/L1-qkv. R12 proved JG=2 loses when weight loads are DIVERGENT;
// R13 made them coalesced (512B contiguous per wave), so doubling their
// count (+2.3K/iter, cheap) to halve broadcast x-LDS reads (-9.2K/iter on
// the serial per-CU LDS pipe, the dominant remaining cost ~55us/iter) is
// now the right trade. Item counts/balance/serial FMA depth identical to
// R13. acc[2][4]+w[8]+xv[4] ~ 30 live VGPR - inside the 64 wall.
// W2/Wo stay JG=1 T=4. Host falls back to R10-style path if ws too small.

#define XS 132
#define QS 388
#define HS 516
#define PS 36
#define VS 36
#define NW 16

// transposed-weight workspace offsets (elements of WT)
#define TWS_QKV0 0        // 384x128
#define TWS_WO0  49152    // 128x128
#define TWS_W10  65536    // 512x128
#define TWS_W20  131072   // 128x512
#define TWS_QKV1 196608   // 256x128 (layer-1 K,V rows)
#define TWS_TOTAL 229376
#define TWS_NVEC (TWS_TOTAL / 4)   // 57344

struct KParams {
  const int* token_ids;
  const unsigned char* pad;
  const void *tok_emb, *pos_emb, *Wqkv, *bqkv, *Wo, *bo, *ln1g, *ln1b;
  const void *W1, *b1, *W2, *b2, *ln2g, *ln2b, *projW, *projb;
  const void *gWih, *gWhh, *gbih, *gbhh;
  const void *accW1, *accb1, *accW2, *accb2;
  const void *emtW1, *emtb1, *emtW2, *emtb2;
  const void *evtW1, *evtb1, *evtW2, *evtb2;
  const void *wst;   // transposed weights (d_ws) or null
  float* out;
};

struct Smem {
  float xbuf[32 * XS];
  float qh[32 * HS];
  float obuf[32 * XS];
  float pbuf[4608];
  float vT[128 * VS];
  float attT[128];
  float tva[128];
  double gild[384];
  double ghld[384];
  double hsd[128];
  double t1d[64];
  double catd[320];
  double hid2d[384];
  double logitsd[3];
  int win_ids[32];
  int sI[6];
  unsigned keyts[32][2];
};

// ---------- typed loads (f32 or bf16) ----------
__device__ __forceinline__ float ldw(const float* p){ return *p; }
__device__ __forceinline__ float ldw(const unsigned short* p){
  return __uint_as_float(((unsigned)*p) << 16);
}
__device__ __forceinline__ float4 ld4(const float* p){ return *(const float4*)p; }
__device__ __forceinline__ float4 ld4(const unsigned short* p){
  ushort4 u = *(const ushort4*)p;
  return make_float4(__uint_as_float((unsigned)u.x << 16),
                     __uint_as_float((unsigned)u.y << 16),
                     __uint_as_float((unsigned)u.z << 16),
                     __uint_as_float((unsigned)u.w << 16));
}
template<typename WT>
__device__ __forceinline__ double ldwd(const WT* p){ return (double)ldw(p); }

__device__ __forceinline__ float temb(const void* te, int isb, long long idx){
  if (isb) return __uint_as_float(((unsigned)((const unsigned short*)te)[idx]) << 16);
  return ((const float*)te)[idx];
}

// ---------- JAX threefry2x32 (partitionable) ----------
__device__ __forceinline__ void tfry(unsigned k0, unsigned k1, unsigned x0, unsigned x1,
                                     unsigned &o0, unsigned &o1){
  unsigned ks2 = k0 ^ k1 ^ 0x1BD11BDAu;
  unsigned x = x0 + k0, y = x1 + k1;
#define TFR(r) { x += y; y = (y << r) | (y >> (32 - r)); y ^= x; }
  TFR(13) TFR(15) TFR(26) TFR(6)  x += k1;  y += ks2 + 1u;
  TFR(17) TFR(29) TFR(16) TFR(24) x += ks2; y += k0 + 2u;
  TFR(13) TFR(15) TFR(26) TFR(6)  x += k0;  y += k1 + 3u;
  TFR(17) TFR(29) TFR(16) TFR(24) x += k1;  y += ks2 + 4u;
  TFR(13) TFR(15) TFR(26) TFR(6)  x += ks2; y += k0 + 5u;
#undef TFR
  o0 = x; o1 = y;
}
__device__ __forceinline__ float u01(unsigned bits){
  return __uint_as_float((bits >> 9) | 0x3f800000u) - 1.0f;
}
__device__ __forceinline__ double logsigd(double x){
  return fmin(x, 0.0) - log1p(exp(-fabs(x)));
}
__device__ __forceinline__ float wredsum(float v, int width){
  for (int m = width >> 1; m > 0; m >>= 1) v += __shfl_xor(v, m, width);
  return v;
}
__device__ __forceinline__ double wredsumd(double v, int width){
  for (int m = width >> 1; m > 0; m >>= 1) v += __shfl_xor(v, m, width);
  return v;
}
__device__ __forceinline__ float dot4f(float4 a, float4 b){
  return a.x*b.x + a.y*b.y + a.z*b.z + a.w*b.w;
}

// ---------- weight transpose pre-pass ----------
// dst vector index local = cg*(K/4)*64 + (k/4)*64 + lane holds
// src elements W[(cg*64+lane)*K + k .. +3]. One thread per 4-elem vector.
__global__ __launch_bounds__(256) void transpose_w_kernel(
    const void* Wqkv, const void* Wo, const void* W1, const void* W2,
    const void* ln1g, void* ws)
{
  const bool isb = (((const unsigned short*)ln1g)[0] == (unsigned short)0x3F80);
  int i = blockIdx.x * 256 + threadIdx.x;
  if (i >= TWS_NVEC) return;
  const void* src; int K4; long long srcBase; int dstBase; int local;
  if (i < 12288)      { src = Wqkv; K4 = 32;  local = i;         srcBase = 0;               dstBase = TWS_QKV0; }
  else if (i < 16384) { src = Wo;   K4 = 32;  local = i - 12288; srcBase = 0;               dstBase = TWS_WO0; }
  else if (i < 32768) { src = W1;   K4 = 32;  local = i - 16384; srcBase = 0;               dstBase = TWS_W10; }
  else if (i < 49152) { src = W2;   K4 = 128; local = i - 32768; srcBase = 0;               dstBase = TWS_W20; }
  else                { src = Wqkv; K4 = 32;  local = i - 49152; srcBase = 384*128+128*128; dstBase = TWS_QKV1; }
  const int per = K4 * 64;
  const int cg = local / per, rem = local % per;
  const int k4 = rem / 64, lane = rem % 64;
  const long long srcElem = srcBase + (long long)(cg * 64 + lane) * (K4 * 4) + (long long)k4 * 4;
  const long long dstElem = (long long)dstBase + (long long)local * 4;
  if (isb) ((uint2*)ws)[dstElem >> 2] = ((const uint2*)src)[srcElem >> 2];
  else     ((uint4*)ws)[dstElem >> 2] = ((const uint4*)src)[srcElem >> 2];
}

// out[tok][j] = bias[j] + sum_k W[j][k]*x[tok][k]; lane=j mod 64,
// T tokens share one weight fetch. TRW: weights read from the lane-major
// transposed tile (coalesced 512B wave-loads). JG=2: item covers column
// groups jp*2 and jp*2+1; one broadcast x-read feeds both accumulators.
// If VOFF >= 0, columns j >= VOFF are V columns -> vt transposed.
template<int T, int K, bool RELU, int VOFF, bool TRW, int JG, typename WT>
__device__ void gemm_tok(const WT* __restrict__ Wm, const WT* __restrict__ Wt,
                         const WT* __restrict__ bias,
                         int J, const float* __restrict__ xl, int xs,
                         float* __restrict__ ol, int os, int ntok,
                         int lane, int wv, int nwv, float* __restrict__ vt)
{
  const int JP = (J >> 6) / JG;
  const int ntt = (ntok + T - 1) / T;
  const size_t cgStride = (size_t)(K / 4) * 64 * 4;
  for (int item = wv; item < JP * ntt; item += nwv) {
    const int jp = item % JP, tt = item / JP;
    const float* xr = xl + tt * T * xs;
    if (JG == 1) {
      const int j0 = jp * 64 + lane;
      float acc[T];
#pragma unroll
      for (int t = 0; t < T; ++t) acc[t] = 0.f;
      const WT* wr0 = TRW ? (Wt + (size_t)jp * cgStride + (size_t)lane * 4)
                          : (Wm + (size_t)j0 * K);
      const WT* wrp = wr0;
#pragma unroll 4
      for (int k = 0; k < K; k += 4) {
        float4 w;
        if (TRW) { w = ld4(wrp); wrp += 256; }
        else     { w = ld4(wr0 + k); }
        float4 xv[T];
#pragma unroll
        for (int t = 0; t < T; ++t) xv[t] = *(const float4*)(xr + t * xs + k);
#pragma unroll
        for (int t = 0; t < T; ++t)
          acc[t] += w.x * xv[t].x + w.y * xv[t].y + w.z * xv[t].z + w.w * xv[t].w;
      }
      float bj = ldw(bias + j0);
#pragma unroll
      for (int t = 0; t < T; ++t) {
        int tok = tt * T + t;
        if (tok < ntok) {
          float v = acc[t] + bj;
          if (RELU) v = fmaxf(v, 0.f);
          if (VOFF >= 0 && j0 >= VOFF) vt[(j0 - VOFF) * VS + tok] = v;
          else                         ol[tok * os + j0] = v;
        }
      }
    } else {
      const int j0 = jp * 128 + lane;
      const int j1 = j0 + 64;
      float acc0[T], acc1[T];
#pragma unroll
      for (int t = 0; t < T; ++t) { acc0[t] = 0.f; acc1[t] = 0.f; }
      const WT* w0p;
      const WT* w1p;
      if (TRW) {
        w0p = Wt + (size_t)(jp * 2) * cgStride + (size_t)lane * 4;
        w1p = w0p + cgStride;
      } else {
        w0p = Wm + (size_t)j0 * K;
        w1p = Wm + (size_t)j1 * K;
      }
#pragma unroll 2
      for (int k = 0; k < K; k += 4) {
        float4 w0, w1;
        if (TRW) { w0 = ld4(w0p); w1 = ld4(w1p); w0p += 256; w1p += 256; }
        else     { w0 = ld4(w0p + k); w1 = ld4(w1p + k); }
#pragma unroll
        for (int t = 0; t < T; ++t) {
          float4 xv = *(const float4*)(xr + t * xs + k);
          acc0[t] += w0.x * xv.x + w0.y * xv.y + w0.z * xv.z + w0.w * xv.w;
          acc1[t] += w1.x * xv.x + w1.y * xv.y + w1.z * xv.z + w1.w * xv.w;
        }
      }
      float b0 = ldw(bias + j0), b1v = ldw(bias + j1);
#pragma unroll
      for (int t = 0; t < T; ++t) {
        int tok = tt * T + t;
        if (tok < ntok) {
          float v0 = acc0[t] + b0, v1 = acc1[t] + b1v;
          if (RELU) { v0 = fmaxf(v0, 0.f); v1 = fmaxf(v1, 0.f); }
          if (VOFF >= 0 && j0 >= VOFF) vt[(j0 - VOFF) * VS + tok] = v0;
          else                         ol[tok * os + j0] = v0;
          if (VOFF >= 0 && j1 >= VOFF) vt[(j1 - VOFF) * VS + tok] = v1;
          else                         ol[tok * os + j1] = v1;
        }
      }
    }
  }
}

template<int K, typename WT>
__device__ __forceinline__ float dotgf(const WT* __restrict__ w, const float* x){
  float acc = 0.f;
#pragma unroll 8
  for (int k = 0; k < K; k += 4) {
    float4 wv = ld4(w + k);
    acc += wv.x * x[k] + wv.y * x[k+1] + wv.z * x[k+2] + wv.w * x[k+3];
  }
  return acc;
}
template<int K, typename WT>
__device__ __forceinline__ double dotgd(const WT* __restrict__ w, const double* x){
  double acc = 0.0;
#pragma unroll 8
  for (int k = 0; k < K; k += 4) {
    float4 wv = ld4(w + k);
    acc += (double)wv.x * x[k] + (double)wv.y * x[k+1]
         + (double)wv.z * x[k+2] + (double)wv.w * x[k+3];
  }
  return acc;
}
template<int K, typename WT>
__device__ __forceinline__ double dotgdx(const WT* __restrict__ w, const float* x){
  double acc = 0.0;
#pragma unroll 8
  for (int k = 0; k < K; k += 4) {
    float4 wv = ld4(w + k);
    acc += (double)wv.x * (double)x[k] + (double)wv.y * (double)x[k+1]
         + (double)wv.z * (double)x[k+2] + (double)wv.w * (double)x[k+3];
  }
  return acc;
}

template<typename WT>
__device__ void ln_rows(float* xb, const float* ob, const WT* __restrict__ g,
                        const WT* __restrict__ bb, int W, int tid){
  if (tid >= 256) return;
  const int i = tid >> 3, sub = tid & 7;
  const int base = i * XS + sub * 16;
  float y[16];
  float s = 0.f;
#pragma unroll
  for (int u = 0; u < 16; u += 4) {
    float4 xv = *(const float4*)(xb + base + u);
    float4 ov = *(const float4*)(ob + base + u);
    y[u] = xv.x + ov.x; y[u+1] = xv.y + ov.y; y[u+2] = xv.z + ov.z; y[u+3] = xv.w + ov.w;
    s += y[u] + y[u+1] + y[u+2] + y[u+3];
  }
  s = wredsum(s, 8);
  const float m = s * (1.0f / 128.0f);
  float vs = 0.f;
#pragma unroll
  for (int u = 0; u < 16; ++u) { float d = y[u] - m; vs += d * d; }
  vs = wredsum(vs, 8);
  const float rstd = 1.0f / sqrtf(vs * (1.0f / 128.0f) + 1e-5f);
  if (i < W) {
#pragma unroll
    for (int u = 0; u < 16; u += 4) {
      float4 gg = ld4(g + sub * 16 + u);
      float4 bv = ld4(bb + sub * 16 + u);
      float4 r;
      r.x = (y[u]   - m) * rstd * gg.x + bv.x;
      r.y = (y[u+1] - m) * rstd * gg.y + bv.y;
      r.z = (y[u+2] - m) * rstd * gg.z + bv.z;
      r.w = (y[u+3] - m) * rstd * gg.w + bv.w;
      *(float4*)(xb + base + u) = r;
    }
  }
}
template<typename WT>
__device__ __forceinline__ void ln_tail(float* xrow, const float* add,
                                        const WT* __restrict__ g,
                                        const WT* __restrict__ bb, int tid){
  if (tid < 64) {
    float y0 = xrow[tid] + add[tid];
    float y1 = xrow[64 + tid] + add[64 + tid];
    float m = wredsum(y0 + y1, 64) * (1.0f / 128.0f);
    float d0 = y0 - m, d1 = y1 - m;
    float rstd = 1.0f / sqrtf(wredsum(d0 * d0 + d1 * d1, 64) * (1.0f / 128.0f) + 1e-5f);
    xrow[tid] = d0 * rstd * ldw(g + tid) + ldw(bb + tid);
    xrow[64 + tid] = d1 * rstd * ldw(g + 64 + tid) + ldw(bb + 64 + tid);
  }
}

template<typename WT, bool TRW>
__device__ void run_all(const KParams& P, Smem& S, int row, int tid, int isbEmb){
  const WT* tok_embw = (const WT*)P.tok_emb;
  const WT* pos_emb = (const WT*)P.pos_emb;
  const WT* Wqkv = (const WT*)P.Wqkv;   const WT* bqkv = (const WT*)P.bqkv;
  const WT* Wo = (const WT*)P.Wo;       const WT* bo = (const WT*)P.bo;
  const WT* ln1g = (const WT*)P.ln1g;   const WT* ln1b = (const WT*)P.ln1b;
  const WT* W1 = (const WT*)P.W1;       const WT* b1 = (const WT*)P.b1;
  const WT* W2 = (const WT*)P.W2;       const WT* b2 = (const WT*)P.b2;
  const WT* ln2g = (const WT*)P.ln2g;   const WT* ln2b = (const WT*)P.ln2b;
  const WT* projW = (const WT*)P.projW; const WT* projb = (const WT*)P.projb;
  const WT* gWih = (const WT*)P.gWih;   const WT* gWhh = (const WT*)P.gWhh;
  const WT* gbih = (const WT*)P.gbih;   const WT* gbhh = (const WT*)P.gbhh;
  const WT* accW1 = (const WT*)P.accW1; const WT* accb1 = (const WT*)P.accb1;
  const WT* accW2 = (const WT*)P.accW2; const WT* accb2 = (const WT*)P.accb2;
  const WT* emtW1 = (const WT*)P.emtW1; const WT* emtb1 = (const WT*)P.emtb1;
  const WT* emtW2 = (const WT*)P.emtW2; const WT* emtb2 = (const WT*)P.emtb2;
  const WT* evtW1 = (const WT*)P.evtW1; const WT* evtb1 = (const WT*)P.evtb1;
  const WT* evtW2 = (const WT*)P.evtW2; const WT* evtb2 = (const WT*)P.evtb2;
  const WT* wsb = (const WT*)P.wst;

  const int lane = tid & 63, wid = tid >> 6;

  if (tid == 0) {
    int seq = 0;
    for (int l = 0; l < 64; ++l) seq += (P.pad[row * 64 + l] == 0);
    S.sI[0] = 0; S.sI[1] = 0; S.sI[2] = (seq == 0) ? 1 : 0; S.sI[3] = seq; S.sI[4] = 0;
  }
  if (tid < 128) S.hsd[tid] = 0.0;
  if (tid < 32) {
    S.win_ids[tid] = 0;
    unsigned a0, a1;
    tfry(0u, 42u, 0u, (unsigned)tid, a0, a1);
    S.keyts[tid][0] = a0; S.keyts[tid][1] = a1;
  }
  for (int idx = tid; idx < 128 * VS; idx += 1024) S.vT[idx] = 0.f;
  __syncthreads();

  for (int t = 0; t < 32; ++t) {
    const int wl = S.sI[0], ip = S.sI[1], done = S.sI[2], seq = S.sI[3];
    const int act = !done;
    const int W = wl;
    const int enc = (act && wl > 0) ? 1 : 0;
    const int jl = (W > 0) ? (W - 1) : 0;
    const int Wp4 = (W + 3) & ~3;

    if (enc) {
      // embedding fill, 8 elems/thread, vectorized
      for (int idx = tid; idx < W * 16; idx += 1024) {
        int i = idx >> 4, d0 = (idx & 15) << 3;
        const WT* te = tok_embw + (long long)S.win_ids[i] * 128 + d0;
        const WT* pe = pos_emb + (size_t)i * 128 + d0;
        float4 t0 = ld4(te), t1 = ld4(te + 4), p0 = ld4(pe), p1 = ld4(pe + 4);
        float* dst = &S.xbuf[i * XS + d0];
        float4 r0, r1;
        r0.x = t0.x + p0.x; r0.y = t0.y + p0.y; r0.z = t0.z + p0.z; r0.w = t0.w + p0.w;
        r1.x = t1.x + p1.x; r1.y = t1.y + p1.y; r1.z = t1.z + p1.z; r1.w = t1.w + p1.w;
        *(float4*)dst = r0;
        *(float4*)(dst + 4) = r1;
      }
      __syncthreads();
      // ---------------- layer 0 (full) ----------------
      gemm_tok<4, 128, false, 256, TRW, 2>(Wqkv, wsb + TWS_QKV0, bqkv, 384,
                                           S.xbuf, XS, S.qh, QS, W, lane, wid, NW, S.vT);
      __syncthreads();
      // scores+softmax on tid<256  ||  GRU ghl (prev-iter hsd) on tid 256..1023
      if (tid < 256) {
        int r = tid >> 1, half = tid & 1;
        int h = r >> 5, i = r & 31;
        if (i < W) {
          float4 q[8];
#pragma unroll
          for (int kk = 0; kk < 8; ++kk) q[kk] = *(const float4*)&S.qh[i * QS + h * 32 + kk * 4];
          const int pb = r * PS;
          const int j0 = half * 16;
          const int j1 = (j0 + 16 < W) ? (j0 + 16) : W;
          float m = -1e30f;
          for (int j = j0; j < j1; ++j) {
            float s = 0.f;
#pragma unroll
            for (int kk = 0; kk < 8; ++kk)
              s += dot4f(q[kk], *(const float4*)&S.qh[j * QS + 128 + h * 32 + kk * 4]);
            s *= 0.17677669529663687f;
            S.pbuf[pb + j] = s;
            m = fmaxf(m, s);
          }
          m = fmaxf(m, __shfl_xor(m, 1, 64));
          float sum = 0.f;
          for (int j = j0; j < j1; ++j) {
            float e = expf(S.pbuf[pb + j] - m);
            S.pbuf[pb + j] = e;
            sum += e;
          }
          sum += __shfl_xor(sum, 1, 64);
          float rs = 1.0f / sum;
          for (int j = j0; j < j1; ++j) S.pbuf[pb + j] *= rs;
          for (int j = W + half; j < Wp4; j += 2) S.pbuf[pb + j] = 0.f;
        }
      } else if (act) {
        int jj = tid - 256;          // 0..767
        int j = jj >> 1, h = jj & 1; // lane pairs, same wave
        double v = dotgd<64>(gWhh + (size_t)j * 128 + h * 64, S.hsd + h * 64);
        v += __shfl_xor(v, 1, 64);
        if (h == 0) S.ghld[j] = ldwd(gbhh + j) + v;
      }
      __syncthreads();
      // AV via transposed V: float4 over j for probs and V
      {
        int c = tid & 127, g = tid >> 7;
        int h = c >> 5;
        const float* vrow = &S.vT[c * VS];
        for (int i = g; i < W; i += 8) {
          const float* prow = &S.pbuf[(h * 32 + i) * PS];
          float acc = 0.f;
          for (int j4 = 0; j4 < W; j4 += 4) {
            float4 p = *(const float4*)(prow + j4);
            float4 v = *(const float4*)(vrow + j4);
            acc += p.x * v.x + p.y * v.y + p.z * v.z + p.w * v.w;
          }
          S.obuf[i * XS + c] = acc;
        }
      }
      __syncthreads();
      gemm_tok<4, 128, false, -1, TRW, 1>(Wo, wsb + TWS_WO0, bo, 128,
                                          S.obuf, XS, S.pbuf, XS, W, lane, wid, NW, S.vT);
      __syncthreads();
      ln_rows(S.xbuf, S.pbuf, ln1g, ln1b, W, tid);
      __syncthreads();
      gemm_tok<4, 128, true, -1, TRW, 2>(W1, wsb + TWS_W10, b1, 512,
                                         S.xbuf, XS, S.qh, HS, W, lane, wid, NW, S.vT);
      __syncthreads();
      // W2: T=4 -> 16 balanced items (R10 win)
      gemm_tok<4, 512, false, -1, TRW, 1>(W2, wsb + TWS_W20, b2, 128,
                                          S.qh, HS, S.obuf, XS, W, lane, wid, NW, S.vT);
      __syncthreads();
      ln_rows(S.xbuf, S.obuf, ln2g, ln2b, W, tid);
      __syncthreads();
      // ---------------- layer 1 (last-token only) ----------------
      {
        const WT* Wq = Wqkv + 384 * 128;
        const WT* bq = bqkv + 384;
        if (wid < 14) {
          gemm_tok<4, 128, false, 128, TRW, 2>(Wq + 128 * 128, wsb + TWS_QKV1, bq + 128, 256,
                                               S.xbuf, XS, S.qh + 128, QS, W, lane, wid, 14, S.vT);
        } else {
          int j = tid - 896;  // 0..127
          S.qh[jl * QS + j] = ldw(bq + j) + dotgf<128>(Wq + j * 128, &S.xbuf[jl * XS]);
        }
        __syncthreads();
        // L1 scores on tid<128  ||  catd-emb gather on tid 896..1023
        if (tid < 128) {
          int h = tid >> 5, j = tid & 31;
          float s = -1e30f;
          if (j < W) {
            s = 0.f;
#pragma unroll
            for (int kk = 0; kk < 8; ++kk)
              s += dot4f(*(const float4*)&S.qh[jl * QS + h * 32 + kk * 4],
                         *(const float4*)&S.qh[j * QS + 128 + h * 32 + kk * 4]);
            s *= 0.17677669529663687f;
          }
          float m = s;
          for (int mk = 16; mk; mk >>= 1) m = fmaxf(m, __shfl_xor(m, mk, 32));
          float e = (j < W) ? expf(s - m) : 0.f;
          float sum = e;
          for (int mk = 16; mk; mk >>= 1) sum += __shfl_xor(sum, mk, 32);
          if (j < W) S.pbuf[h * PS + j] = e * (1.0f / sum);
          else       S.pbuf[h * PS + j] = 0.f;
        } else if (tid >= 896) {
          int j = tid - 896;
          int ipc = ip < 0 ? 0 : (ip > 63 ? 63 : ip);
          int nt = P.token_ids[row * 64 + ipc];
          int has_in = (act && (ip < seq)) ? 1 : 0;
          S.catd[j] = has_in ? (double)temb(P.tok_emb, isbEmb, (long long)nt * 128 + j) : 0.0;
        }
        __syncthreads();
        if (tid < 128) {
          int h = tid >> 5;
          const float* prow = &S.pbuf[h * PS];
          const float* vrow = &S.vT[tid * VS];
          float acc = 0.f;
          for (int j4 = 0; j4 < W; j4 += 4) {
            float4 p = *(const float4*)(prow + j4);
            float4 v = *(const float4*)(vrow + j4);
            acc += p.x * v.x + p.y * v.y + p.z * v.z + p.w * v.w;
          }
          S.attT[tid] = acc;
        }
        __syncthreads();
        // Wo tail, widened 4-way k-split
        if (tid < 512) {
          int j = tid >> 2, q = tid & 3;
          float v = dotgf<32>(Wo + 16384 + (size_t)j * 128 + q * 32, S.attT + q * 32);
          v += __shfl_xor(v, 1, 64);
          v += __shfl_xor(v, 2, 64);
          if (q == 0) S.tva[j] = ldw(bo + 128 + j) + v;
        }
        __syncthreads();
        ln_tail(&S.xbuf[jl * XS], S.tva, ln1g + 128, ln1b + 128, tid);
        __syncthreads();
        // W1 tail, widened 2-way k-split (all 1024 threads)
        {
          int j = tid >> 1, h = tid & 1;
          float v = dotgf<64>(W1 + (size_t)(512 + j) * 128 + h * 64, &S.xbuf[jl * XS] + h * 64);
          v += __shfl_xor(v, 1, 64);
          if (h == 0) S.qh[j] = fmaxf(ldw(b1 + 512 + j) + v, 0.f);
        }
        __syncthreads();
        // W2 tail, widened 4-way k-split
        if (tid < 512) {
          int j = tid >> 2, q = tid & 3;
          float v = dotgf<128>(W2 + (size_t)(128 + j) * 512 + q * 128, S.qh + q * 128);
          v += __shfl_xor(v, 1, 64);
          v += __shfl_xor(v, 2, 64);
          if (q == 0) S.tva[j] = ldw(b2 + 128 + j) + v;
        }
        __syncthreads();
        ln_tail(&S.xbuf[jl * XS], S.tva, ln2g + 128, ln2b + 128, tid);
        __syncthreads();
      }
    }

    // ---- stage A: proj->t1 (+ ghl/catd-emb only when encoder skipped) ----
    if (tid < 64) {
      double tv = 0.0;
      if (enc) {
        double v = ldwd(projb + tid) + dotgdx<128>(projW + tid * 128, &S.xbuf[jl * XS]);
        double ss = wredsumd(v * v, 64);
        tv = v / fmax(sqrt(ss), 1e-12);
      }
      S.t1d[tid] = tv;
      S.catd[128 + tid] = tv;
      P.out[(size_t)t * 4096 + row * 64 + tid] = (float)tv;
    } else if (!enc) {
      if (tid >= 128 && tid < 896) {
        if (act) {
          int jj = tid - 128;          // 0..767
          int j = jj >> 1, h = jj & 1; // lane pairs, same wave
          double v = dotgd<64>(gWhh + (size_t)j * 128 + h * 64, S.hsd + h * 64);
          v += __shfl_xor(v, 1, 64);
          if (h == 0) S.ghld[j] = ldwd(gbhh + j) + v;
        }
      } else if (tid >= 896) {
        int j = tid - 896;
        int ipc = ip < 0 ? 0 : (ip > 63 ? 63 : ip);
        int nt = P.token_ids[row * 64 + ipc];
        int has_in = (act && (ip < seq)) ? 1 : 0;
        S.catd[j] = has_in ? (double)temb(P.tok_emb, isbEmb, (long long)nt * 128 + j) : 0.0;
      }
    }
    __syncthreads();

    // ---- stage B: gil (needs t1), widened 2-way ----
    if (act) {
      if (tid < 768) {
        int j = tid >> 1, h = tid & 1;
        double v = dotgd<32>(gWih + (size_t)j * 64 + h * 32, S.t1d + h * 32);
        v += __shfl_xor(v, 1, 64);
        if (h == 0) S.gild[j] = ldwd(gbih + j) + v;
      }
      __syncthreads();
    }

    // ---- stage C: hsd update + catd-h ----
    if (tid < 128) {
      if (act) {
        double r = 1.0 / (1.0 + exp(-(S.gild[tid] + S.ghld[tid])));
        double z = 1.0 / (1.0 + exp(-(S.gild[128 + tid] + S.ghld[128 + tid])));
        double n = tanh(S.gild[256 + tid] + r * S.ghld[256 + tid]);
        S.hsd[tid] = (1.0 - z) * n + z * S.hsd[tid];
      }
      S.catd[192 + tid] = S.hsd[tid];
    }
    __syncthreads();

    // ---- stage D: three head hidden layers, widened 2-way k-split ----
    if (tid < 768) {
      int jo = tid >> 1, h = tid & 1;
      double v;
      if (jo < 128) {
        v = dotgd<160>(accW1 + (size_t)jo * 320 + h * 160, S.catd + h * 160);
      } else if (jo < 256) {
        int j = jo - 128;
        v = dotgd<96>(emtW1 + (size_t)j * 192 + h * 96, S.catd + 128 + h * 96);
      } else {
        int j = jo - 256;
        v = dotgd<96>(evtW1 + (size_t)j * 192 + h * 96, S.catd + 128 + h * 96);
      }
      v += __shfl_xor(v, 1, 64);
      if (h == 0) {
        double b = (jo < 128) ? ldwd(accb1 + jo)
                 : (jo < 256 ? ldwd(emtb1 + jo - 128) : ldwd(evtb1 + jo - 256));
        S.hid2d[jo] = fmax(b + v, 0.0);
      }
    }
    __syncthreads();

    // ---- stage E: three logits ----
    {
      int hw = tid >> 6;
      if (hw < 3) {
        int ln = tid & 63;
        const WT* w2 = (hw == 0) ? accW2 : ((hw == 1) ? emtW2 : evtW2);
        const WT* b2p = (hw == 0) ? accb2 : ((hw == 1) ? emtb2 : evtb2);
        double pp = S.hid2d[hw * 128 + ln] * ldwd(w2 + ln)
                  + S.hid2d[hw * 128 + 64 + ln] * ldwd(w2 + 64 + ln);
        pp = wredsumd(pp, 64);
        if (ln == 0) S.logitsd[hw] = pp + ldwd(b2p);
      }
    }
    __syncthreads();

    // ---- stage F: sample (3 lanes in parallel) + state update (lane 0) ----
    if (tid < 64) {
      unsigned k0 = S.keyts[t][0], k1 = S.keyts[t][1];
      int smp_l = 0;
      if (tid < 3) {
        double lgv = S.logitsd[tid];
        unsigned sk0, sk1, r0, r1;
        tfry(k0, k1, 0u, (unsigned)tid, sk0, sk1);
        tfry(sk0, sk1, 0u, (unsigned)row, r0, r1);
        double u = (double)u01(r0 ^ r1);
        double p = 1.0 / (1.0 + exp(-lgv));
        smp_l = (u < p) ? 1 : 0;
        P.out[131072 + (size_t)t * 192 + row * 3 + tid] = (float)logsigd(smp_l ? lgv : -lgv);
        P.out[137216 + (size_t)t * 192 + row * 3 + tid] = smp_l ? 1.0f : 0.0f;
      }
      int sa = __shfl(smp_l, 0, 64);
      int se = __shfl(smp_l, 1, 64);
      int sv = __shfl(smp_l, 2, 64);
      if (tid == 0) {
        int wl2 = wl, ip2 = ip, dn = done;
        int nonempty = (wl2 > 0) && act;
        int has_in = act && (ip2 < seq);
        int a = sa && has_in;
        int e = se && nonempty;
        int v = sv && nonempty;
        int none = act && !(a || e || v);
        a = a || (none && has_in);
        e = e || (none && !has_in && (wl2 > 0));
        int aeff = a && (wl2 < 32);
        int ipc = ip2 < 0 ? 0 : (ip2 > 63 ? 63 : ip2);
        int nt = P.token_ids[row * 64 + ipc];
        if (aeff) { S.win_ids[wl2] = nt; ip2 += 1; wl2 += 1; }
        int emit = e && (wl2 > 0);
        S.sI[4] += emit;
        int veff = v && (wl2 > 0);
        if (veff) {
          int w0 = S.win_ids[0];
#pragma unroll
          for (int i2 = 0; i2 < 31; ++i2) S.win_ids[i2] = S.win_ids[i2 + 1];
          S.win_ids[31] = w0;
          wl2 -= 1;
        }
        if (act && (ip2 >= seq) && (wl2 == 0)) dn = 1;
        S.sI[0] = wl2; S.sI[1] = ip2; S.sI[2] = dn;
      }
    }
    __syncthreads();
  }
  if (tid == 0) P.out[143360 + row] = (float)S.sI[4];
}

template<bool TRW>
__global__ __launch_bounds__(1024, 4) void src_main_kernel_t(KParams P){
  __shared__ __align__(16) Smem S;
  const int row = blockIdx.x;
  const int tid = threadIdx.x;
  const bool isb = (((const unsigned short*)P.ln1g)[0] == (unsigned short)0x3F80);
  if (isb) run_all<unsigned short, TRW>(P, S, row, tid, 1);
  else     run_all<float, TRW>(P, S, row, tid, 0);
}

extern "C" void kernel_launch(void* const* d_in, const int* in_sizes, int n_in,
                              void* d_out, int out_size, void* d_ws, size_t ws_size,
                              hipStream_t stream) {
  KParams P;
  P.token_ids = (const int*)d_in[0];
  P.pad = (const unsigned char*)d_in[1];
  P.tok_emb = d_in[4];  P.pos_emb = d_in[5];
  P.Wqkv = d_in[6];     P.bqkv = d_in[7];
  P.Wo = d_in[8];       P.bo = d_in[9];
  P.ln1g = d_in[10];    P.ln1b = d_in[11];
  P.W1 = d_in[12];      P.b1 = d_in[13];
  P.W2 = d_in[14];      P.b2 = d_in[15];
  P.ln2g = d_in[16];    P.ln2b = d_in[17];
  P.projW = d_in[18];   P.projb = d_in[19];
  P.gWih = d_in[20];    P.gWhh = d_in[21];
  P.gbih = d_in[22];    P.gbhh = d_in[23];
  P.accW1 = d_in[24];   P.accb1 = d_in[25];
  P.accW2 = d_in[26];   P.accb2 = d_in[27];
  P.emtW1 = d_in[28];   P.emtb1 = d_in[29];
  P.emtW2 = d_in[30];   P.emtb2 = d_in[31];
  P.evtW1 = d_in[32];   P.evtb1 = d_in[33];
  P.evtW2 = d_in[34];   P.evtb2 = d_in[35];
  P.wst = d_ws;
  P.out = (float*)d_out;
  const bool tr = (d_ws != nullptr) && (ws_size >= (size_t)TWS_TOTAL * 4);
  if (tr) {
    hipLaunchKernelGGL(transpose_w_kernel, dim3((TWS_NVEC + 255) / 256), dim3(256), 0, stream,
                       P.Wqkv, P.Wo, P.W1, P.W2, P.ln1g, d_ws);
    hipLaunchKernelGGL((src_main_kernel_t<true>), dim3(64), dim3(1024), 0, stream, P);
  } else {
    hipLaunchKernelGGL((src_main_kernel_t<false>), dim3(64), dim3(1024), 0, stream, P);
  }
}

// Round 15
// 3922.047 us; speedup vs baseline: 1.1162x; 1.1162x over previous
//
#include <hip/hip_runtime.h>
#include <hip/hip_bf16.h>

// ShiftReduceCompressor: persistent kernel, 1 block/row (B=64), 1024 threads,
// 32-iteration scan in-kernel. Encoder fp32, sampling tail fp64, exact
// partitionable JAX threefry. Fused tail.
//
// Round 15 = R13 (best 4126us; coalesced weight tiles, T=8/JG=1) + 8-wide
// tiles for the two T=4 gemms (Wo, W2): tile layout [cg][k/8][lane][8] so
// one 16B load (bf16 uint4 + R7-verified unpack) delivers 8 weights ->
// halves their coalesced load count (-1.3K/iter). T=4 keeps live set ~30
// VGPR (R7's spill was the T=8 variant). T=8 gemms keep 4-wide tiles
// (xv[8]=32 regs leaves no room for a second weight reg).
// R14 lesson: NEVER drop T (halving T doubled weight re-fetch, FETCH
// 22->48MB, -252us). T=8 token amortization is the dominant invariant.

#define XS 132
#define QS 388
#define HS 516
#define PS 36
#define VS 36
#define NW 16

// transposed-weight workspace offsets (elements of WT)
#define TWS_QKV0 0        // 384x128 (4-wide)
#define TWS_WO0  49152    // 128x128 (8-wide)
#define TWS_W10  65536    // 512x128 (4-wide)
#define TWS_W20  131072   // 128x512 (8-wide)
#define TWS_QKV1 196608   // 256x128 (4-wide; layer-1 K,V rows)
#define TWS_TOTAL 229376
#define TWS_NVEC (TWS_TOTAL / 4)   // 57344

struct KParams {
  const int* token_ids;
  const unsigned char* pad;
  const void *tok_emb, *pos_emb, *Wqkv, *bqkv, *Wo, *bo, *ln1g, *ln1b;
  const void *W1, *b1, *W2, *b2, *ln2g, *ln2b, *projW, *projb;
  const void *gWih, *gWhh, *gbih, *gbhh;
  const void *accW1, *accb1, *accW2, *accb2;
  const void *emtW1, *emtb1, *emtW2, *emtb2;
  const void *evtW1, *evtb1, *evtW2, *evtb2;
  const void *wst;   // transposed weights (d_ws) or null
  float* out;
};

struct Smem {
  float xbuf[32 * XS];
  float qh[32 * HS];
  float obuf[32 * XS];
  float pbuf[4608];
  float vT[128 * VS];
  float attT[128];
  float tva[128];
  double gild[384];
  double ghld[384];
  double hsd[128];
  double t1d[64];
  double catd[320];
  double hid2d[384];
  double logitsd[3];
  int win_ids[32];
  int sI[6];
  unsigned keyts[32][2];
};

// ---------- typed loads (f32 or bf16) ----------
__device__ __forceinline__ float ldw(const float* p){ return *p; }
__device__ __forceinline__ float ldw(const unsigned short* p){
  return __uint_as_float(((unsigned)*p) << 16);
}
__device__ __forceinline__ float4 ld4(const float* p){ return *(const float4*)p; }
__device__ __forceinline__ float4 ld4(const unsigned short* p){
  ushort4 u = *(const ushort4*)p;
  return make_float4(__uint_as_float((unsigned)u.x << 16),
                     __uint_as_float((unsigned)u.y << 16),
                     __uint_as_float((unsigned)u.z << 16),
                     __uint_as_float((unsigned)u.w << 16));
}
// 8 consecutive elems in one shot (bf16: one 16B uint4 + unpack; f32: two float4)
__device__ __forceinline__ void ld8(const float* p, float4& a, float4& b){
  a = *(const float4*)p; b = *(const float4*)(p + 4);
}
__device__ __forceinline__ void ld8(const unsigned short* p, float4& a, float4& b){
  uint4 u = *(const uint4*)p;
  a.x = __uint_as_float(u.x << 16); a.y = __uint_as_float(u.x & 0xffff0000u);
  a.z = __uint_as_float(u.y << 16); a.w = __uint_as_float(u.y & 0xffff0000u);
  b.x = __uint_as_float(u.z << 16); b.y = __uint_as_float(u.z & 0xffff0000u);
  b.z = __uint_as_float(u.w << 16); b.w = __uint_as_float(u.w & 0xffff0000u);
}
template<typename WT>
__device__ __forceinline__ double ldwd(const WT* p){ return (double)ldw(p); }

__device__ __forceinline__ float temb(const void* te, int isb, long long idx){
  if (isb) return __uint_as_float(((unsigned)((const unsigned short*)te)[idx]) << 16);
  return ((const float*)te)[idx];
}

// ---------- JAX threefry2x32 (partitionable) ----------
__device__ __forceinline__ void tfry(unsigned k0, unsigned k1, unsigned x0, unsigned x1,
                                     unsigned &o0, unsigned &o1){
  unsigned ks2 = k0 ^ k1 ^ 0x1BD11BDAu;
  unsigned x = x0 + k0, y = x1 + k1;
#define TFR(r) { x += y; y = (y << r) | (y >> (32 - r)); y ^= x; }
  TFR(13) TFR(15) TFR(26) TFR(6)  x += k1;  y += ks2 + 1u;
  TFR(17) TFR(29) TFR(16) TFR(24) x += ks2; y += k0 + 2u;
  TFR(13) TFR(15) TFR(26) TFR(6)  x += k0;  y += k1 + 3u;
  TFR(17) TFR(29) TFR(16) TFR(24) x += k1;  y += ks2 + 4u;
  TFR(13) TFR(15) TFR(26) TFR(6)  x += ks2; y += k0 + 5u;
#undef TFR
  o0 = x; o1 = y;
}
__device__ __forceinline__ float u01(unsigned bits){
  return __uint_as_float((bits >> 9) | 0x3f800000u) - 1.0f;
}
__device__ __forceinline__ double logsigd(double x){
  return fmin(x, 0.0) - log1p(exp(-fabs(x)));
}
__device__ __forceinline__ float wredsum(float v, int width){
  for (int m = width >> 1; m > 0; m >>= 1) v += __shfl_xor(v, m, width);
  return v;
}
__device__ __forceinline__ double wredsumd(double v, int width){
  for (int m = width >> 1; m > 0; m >>= 1) v += __shfl_xor(v, m, width);
  return v;
}
__device__ __forceinline__ float dot4f(float4 a, float4 b){
  return a.x*b.x + a.y*b.y + a.z*b.z + a.w*b.w;
}

// ---------- weight transpose pre-pass ----------
// 4-wide blocks: dst 4-vec local = cg*(K/4)*64 + (k/4)*64 + lane holds
//   W[(cg*64+lane)*K + k..k+3].
// 8-wide blocks (Wo, W2): dst elems ((cg*(K/8)+k8)*64+lane)*8 + e4*4 hold
//   W[(cg*64+lane)*K + k8*8 + e4*4 ..+3]. One thread per 4-elem vector.
__global__ __launch_bounds__(256) void transpose_w_kernel(
    const void* Wqkv, const void* Wo, const void* W1, const void* W2,
    const void* ln1g, void* ws)
{
  const bool isb = (((const unsigned short*)ln1g)[0] == (unsigned short)0x3F80);
  int i = blockIdx.x * 256 + threadIdx.x;
  if (i >= TWS_NVEC) return;
  const void* src; int K4; long long srcBase = 0; int dstBase; int local; bool w8 = false;
  if (i < 12288)      { src = Wqkv; K4 = 32;  local = i;         dstBase = TWS_QKV0; }
  else if (i < 16384) { src = Wo;   K4 = 32;  local = i - 12288; dstBase = TWS_WO0;  w8 = true; }
  else if (i < 32768) { src = W1;   K4 = 32;  local = i - 16384; dstBase = TWS_W10; }
  else if (i < 49152) { src = W2;   K4 = 128; local = i - 32768; dstBase = TWS_W20;  w8 = true; }
  else                { src = Wqkv; K4 = 32;  local = i - 49152; srcBase = 384*128+128*128; dstBase = TWS_QKV1; }
  long long srcElem, dstElem;
  if (!w8) {
    const int per = K4 * 64;
    const int cg = local / per, rem = local % per;
    const int k4 = rem / 64, lane = rem % 64;
    srcElem = srcBase + (long long)(cg * 64 + lane) * (K4 * 4) + (long long)k4 * 4;
    dstElem = (long long)dstBase + (long long)local * 4;
  } else {
    const int K8 = K4 >> 1;
    const int e4 = local & 1, r = local >> 1;
    const int lane = r & 63, k8 = (r >> 6) % K8, cg = r / (64 * K8);
    srcElem = srcBase + (long long)(cg * 64 + lane) * (K4 * 4) + (long long)k8 * 8 + e4 * 4;
    dstElem = (long long)dstBase + ((long long)((cg * K8 + k8) * 64 + lane)) * 8 + e4 * 4;
  }
  if (isb) ((uint2*)ws)[dstElem >> 2] = ((const uint2*)src)[srcElem >> 2];
  else     ((uint4*)ws)[dstElem >> 2] = ((const uint4*)src)[srcElem >> 2];
}

// out[tok][j] = bias[j] + sum_k W[j][k]*x[tok][k]; lane=j mod 64,
// T tokens share one weight fetch. TRW: coalesced lane-major tiles.
// WW=4: one 16B(f32)/8B(bf16) tile load per k4-step (R13 path).
// WW=8: one 16B load per k8-step delivers 8 weights (Wo/W2, T=4 only).
// If VOFF >= 0, columns j0 >= VOFF are V columns -> vt transposed.
template<int T, int K, bool RELU, int VOFF, bool TRW, int WW, typename WT>
__device__ void gemm_tok(const WT* __restrict__ Wm, const WT* __restrict__ Wt,
                         const WT* __restrict__ bias,
                         int J, const float* __restrict__ xl, int xs,
                         float* __restrict__ ol, int os, int ntok,
                         int lane, int wv, int nwv, float* __restrict__ vt)
{
  const int JBG = J >> 6;
  const int ntt = (ntok + T - 1) / T;
  for (int item = wv; item < JBG * ntt; item += nwv) {
    const int jg = item % JBG, tt = item / JBG;
    const int j0 = jg * 64 + lane;
    float acc[T];
#pragma unroll
    for (int t = 0; t < T; ++t) acc[t] = 0.f;
    const float* xr = xl + tt * T * xs;
    if (WW == 4) {
      const WT* wr0 = TRW ? (Wt + ((size_t)jg * (K / 4) * 64 + lane) * 4)
                          : (Wm + (size_t)j0 * K);
      const WT* wrp = wr0;
#pragma unroll 4
      for (int k = 0; k < K; k += 4) {
        float4 w;
        if (TRW) { w = ld4(wrp); wrp += 256; }
        else     { w = ld4(wr0 + k); }
        float4 xv[T];
#pragma unroll
        for (int t = 0; t < T; ++t) xv[t] = *(const float4*)(xr + t * xs + k);
#pragma unroll
        for (int t = 0; t < T; ++t)
          acc[t] += w.x * xv[t].x + w.y * xv[t].y + w.z * xv[t].z + w.w * xv[t].w;
      }
    } else {
      const WT* wr0 = TRW ? (Wt + ((size_t)jg * (K / 8) * 64 + lane) * 8)
                          : (Wm + (size_t)j0 * K);
      const WT* wrp = wr0;
#pragma unroll 2
      for (int k = 0; k < K; k += 8) {
        float4 wA, wB;
        if (TRW) { ld8(wrp, wA, wB); wrp += 512; }
        else     { wA = ld4(wr0 + k); wB = ld4(wr0 + k + 4); }
        float4 xv[T];
#pragma unroll
        for (int t = 0; t < T; ++t) xv[t] = *(const float4*)(xr + t * xs + k);
#pragma unroll
        for (int t = 0; t < T; ++t)
          acc[t] += wA.x * xv[t].x + wA.y * xv[t].y + wA.z * xv[t].z + wA.w * xv[t].w;
#pragma unroll
        for (int t = 0; t < T; ++t) xv[t] = *(const float4*)(xr + t * xs + k + 4);
#pragma unroll
        for (int t = 0; t < T; ++t)
          acc[t] += wB.x * xv[t].x + wB.y * xv[t].y + wB.z * xv[t].z + wB.w * xv[t].w;
      }
    }
    float bj = ldw(bias + j0);
#pragma unroll
    for (int t = 0; t < T; ++t) {
      int tok = tt * T + t;
      if (tok < ntok) {
        float v = acc[t] + bj;
        if (RELU) v = fmaxf(v, 0.f);
        if (VOFF >= 0 && j0 >= VOFF) vt[(j0 - VOFF) * VS + tok] = v;
        else                         ol[tok * os + j0] = v;
      }
    }
  }
}

template<int K, typename WT>
__device__ __forceinline__ float dotgf(const WT* __restrict__ w, const float* x){
  float acc = 0.f;
#pragma unroll 8
  for (int k = 0; k < K; k += 4) {
    float4 wv = ld4(w + k);
    acc += wv.x * x[k] + wv.y * x[k+1] + wv.z * x[k+2] + wv.w * x[k+3];
  }
  return acc;
}
template<int K, typename WT>
__device__ __forceinline__ double dotgd(const WT* __restrict__ w, const double* x){
  double acc = 0.0;
#pragma unroll 8
  for (int k = 0; k < K; k += 4) {
    float4 wv = ld4(w + k);
    acc += (double)wv.x * x[k] + (double)wv.y * x[k+1]
         + (double)wv.z * x[k+2] + (double)wv.w * x[k+3];
  }
  return acc;
}
template<int K, typename WT>
__device__ __forceinline__ double dotgdx(const WT* __restrict__ w, const float* x){
  double acc = 0.0;
#pragma unroll 8
  for (int k = 0; k < K; k += 4) {
    float4 wv = ld4(w + k);
    acc += (double)wv.x * (double)x[k] + (double)wv.y * (double)x[k+1]
         + (double)wv.z * (double)x[k+2] + (double)wv.w * (double)x[k+3];
  }
  return acc;
}

template<typename WT>
__device__ void ln_rows(float* xb, const float* ob, const WT* __restrict__ g,
                        const WT* __restrict__ bb, int W, int tid){
  if (tid >= 256) return;
  const int i = tid >> 3, sub = tid & 7;
  const int base = i * XS + sub * 16;
  float y[16];
  float s = 0.f;
#pragma unroll
  for (int u = 0; u < 16; u += 4) {
    float4 xv = *(const float4*)(xb + base + u);
    float4 ov = *(const float4*)(ob + base + u);
    y[u] = xv.x + ov.x; y[u+1] = xv.y + ov.y; y[u+2] = xv.z + ov.z; y[u+3] = xv.w + ov.w;
    s += y[u] + y[u+1] + y[u+2] + y[u+3];
  }
  s = wredsum(s, 8);
  const float m = s * (1.0f / 128.0f);
  float vs = 0.f;
#pragma unroll
  for (int u = 0; u < 16; ++u) { float d = y[u] - m; vs += d * d; }
  vs = wredsum(vs, 8);
  const float rstd = 1.0f / sqrtf(vs * (1.0f / 128.0f) + 1e-5f);
  if (i < W) {
#pragma unroll
    for (int u = 0; u < 16; u += 4) {
      float4 gg = ld4(g + sub * 16 + u);
      float4 bv = ld4(bb + sub * 16 + u);
      float4 r;
      r.x = (y[u]   - m) * rstd * gg.x + bv.x;
      r.y = (y[u+1] - m) * rstd * gg.y + bv.y;
      r.z = (y[u+2] - m) * rstd * gg.z + bv.z;
      r.w = (y[u+3] - m) * rstd * gg.w + bv.w;
      *(float4*)(xb + base + u) = r;
    }
  }
}
template<typename WT>
__device__ __forceinline__ void ln_tail(float* xrow, const float* add,
                                        const WT* __restrict__ g,
                                        const WT* __restrict__ bb, int tid){
  if (tid < 64) {
    float y0 = xrow[tid] + add[tid];
    float y1 = xrow[64 + tid] + add[64 + tid];
    float m = wredsum(y0 + y1, 64) * (1.0f / 128.0f);
    float d0 = y0 - m, d1 = y1 - m;
    float rstd = 1.0f / sqrtf(wredsum(d0 * d0 + d1 * d1, 64) * (1.0f / 128.0f) + 1e-5f);
    xrow[tid] = d0 * rstd * ldw(g + tid) + ldw(bb + tid);
    xrow[64 + tid] = d1 * rstd * ldw(g + 64 + tid) + ldw(bb + 64 + tid);
  }
}

template<typename WT, bool TRW>
__device__ void run_all(const KParams& P, Smem& S, int row, int tid, int isbEmb){
  const WT* tok_embw = (const WT*)P.tok_emb;
  const WT* pos_emb = (const WT*)P.pos_emb;
  const WT* Wqkv = (const WT*)P.Wqkv;   const WT* bqkv = (const WT*)P.bqkv;
  const WT* Wo = (const WT*)P.Wo;       const WT* bo = (const WT*)P.bo;
  const WT* ln1g = (const WT*)P.ln1g;   const WT* ln1b = (const WT*)P.ln1b;
  const WT* W1 = (const WT*)P.W1;       const WT* b1 = (const WT*)P.b1;
  const WT* W2 = (const WT*)P.W2;       const WT* b2 = (const WT*)P.b2;
  const WT* ln2g = (const WT*)P.ln2g;   const WT* ln2b = (const WT*)P.ln2b;
  const WT* projW = (const WT*)P.projW; const WT* projb = (const WT*)P.projb;
  const WT* gWih = (const WT*)P.gWih;   const WT* gWhh = (const WT*)P.gWhh;
  const WT* gbih = (const WT*)P.gbih;   const WT* gbhh = (const WT*)P.gbhh;
  const WT* accW1 = (const WT*)P.accW1; const WT* accb1 = (const WT*)P.accb1;
  const WT* accW2 = (const WT*)P.accW2; const WT* accb2 = (const WT*)P.accb2;
  const WT* emtW1 = (const WT*)P.emtW1; const WT* emtb1 = (const WT*)P.emtb1;
  const WT* emtW2 = (const WT*)P.emtW2; const WT* emtb2 = (const WT*)P.emtb2;
  const WT* evtW1 = (const WT*)P.evtW1; const WT* evtb1 = (const WT*)P.evtb1;
  const WT* evtW2 = (const WT*)P.evtW2; const WT* evtb2 = (const WT*)P.evtb2;
  const WT* wsb = (const WT*)P.wst;

  const int lane = tid & 63, wid = tid >> 6;

  if (tid == 0) {
    int seq = 0;
    for (int l = 0; l < 64; ++l) seq += (P.pad[row * 64 + l] == 0);
    S.sI[0] = 0; S.sI[1] = 0; S.sI[2] = (seq == 0) ? 1 : 0; S.sI[3] = seq; S.sI[4] = 0;
  }
  if (tid < 128) S.hsd[tid] = 0.0;
  if (tid < 32) {
    S.win_ids[tid] = 0;
    unsigned a0, a1;
    tfry(0u, 42u, 0u, (unsigned)tid, a0, a1);
    S.keyts[tid][0] = a0; S.keyts[tid][1] = a1;
  }
  for (int idx = tid; idx < 128 * VS; idx += 1024) S.vT[idx] = 0.f;
  __syncthreads();

  for (int t = 0; t < 32; ++t) {
    const int wl = S.sI[0], ip = S.sI[1], done = S.sI[2], seq = S.sI[3];
    const int act = !done;
    const int W = wl;
    const int enc = (act && wl > 0) ? 1 : 0;
    const int jl = (W > 0) ? (W - 1) : 0;
    const int Wp4 = (W + 3) & ~3;

    if (enc) {
      // embedding fill, 8 elems/thread, vectorized
      for (int idx = tid; idx < W * 16; idx += 1024) {
        int i = idx >> 4, d0 = (idx & 15) << 3;
        const WT* te = tok_embw + (long long)S.win_ids[i] * 128 + d0;
        const WT* pe = pos_emb + (size_t)i * 128 + d0;
        float4 t0 = ld4(te), t1 = ld4(te + 4), p0 = ld4(pe), p1 = ld4(pe + 4);
        float* dst = &S.xbuf[i * XS + d0];
        float4 r0, r1;
        r0.x = t0.x + p0.x; r0.y = t0.y + p0.y; r0.z = t0.z + p0.z; r0.w = t0.w + p0.w;
        r1.x = t1.x + p1.x; r1.y = t1.y + p1.y; r1.z = t1.z + p1.z; r1.w = t1.w + p1.w;
        *(float4*)dst = r0;
        *(float4*)(dst + 4) = r1;
      }
      __syncthreads();
      // ---------------- layer 0 (full) ----------------
      gemm_tok<8, 128, false, 256, TRW, 4>(Wqkv, wsb + TWS_QKV0, bqkv, 384,
                                           S.xbuf, XS, S.qh, QS, W, lane, wid, NW, S.vT);
      __syncthreads();
      // scores+softmax on tid<256  ||  GRU ghl (prev-iter hsd) on tid 256..1023
      if (tid < 256) {
        int r = tid >> 1, half = tid & 1;
        int h = r >> 5, i = r & 31;
        if (i < W) {
          float4 q[8];
#pragma unroll
          for (int kk = 0; kk < 8; ++kk) q[kk] = *(const float4*)&S.qh[i * QS + h * 32 + kk * 4];
          const int pb = r * PS;
          const int j0 = half * 16;
          const int j1 = (j0 + 16 < W) ? (j0 + 16) : W;
          float m = -1e30f;
          for (int j = j0; j < j1; ++j) {
            float s = 0.f;
#pragma unroll
            for (int kk = 0; kk < 8; ++kk)
              s += dot4f(q[kk], *(const float4*)&S.qh[j * QS + 128 + h * 32 + kk * 4]);
            s *= 0.17677669529663687f;
            S.pbuf[pb + j] = s;
            m = fmaxf(m, s);
          }
          m = fmaxf(m, __shfl_xor(m, 1, 64));
          float sum = 0.f;
          for (int j = j0; j < j1; ++j) {
            float e = expf(S.pbuf[pb + j] - m);
            S.pbuf[pb + j] = e;
            sum += e;
          }
          sum += __shfl_xor(sum, 1, 64);
          float rs = 1.0f / sum;
          for (int j = j0; j < j1; ++j) S.pbuf[pb + j] *= rs;
          for (int j = W + half; j < Wp4; j += 2) S.pbuf[pb + j] = 0.f;
        }
      } else if (act) {
        int jj = tid - 256;          // 0..767
        int j = jj >> 1, h = jj & 1; // lane pairs, same wave
        double v = dotgd<64>(gWhh + (size_t)j * 128 + h * 64, S.hsd + h * 64);
        v += __shfl_xor(v, 1, 64);
        if (h == 0) S.ghld[j] = ldwd(gbhh + j) + v;
      }
      __syncthreads();
      // AV via transposed V: float4 over j for probs and V
      {
        int c = tid & 127, g = tid >> 7;
        int h = c >> 5;
        const float* vrow = &S.vT[c * VS];
        for (int i = g; i < W; i += 8) {
          const float* prow = &S.pbuf[(h * 32 + i) * PS];
          float acc = 0.f;
          for (int j4 = 0; j4 < W; j4 += 4) {
            float4 p = *(const float4*)(prow + j4);
            float4 v = *(const float4*)(vrow + j4);
            acc += p.x * v.x + p.y * v.y + p.z * v.z + p.w * v.w;
          }
          S.obuf[i * XS + c] = acc;
        }
      }
      __syncthreads();
      gemm_tok<4, 128, false, -1, TRW, 8>(Wo, wsb + TWS_WO0, bo, 128,
                                          S.obuf, XS, S.pbuf, XS, W, lane, wid, NW, S.vT);
      __syncthreads();
      ln_rows(S.xbuf, S.pbuf, ln1g, ln1b, W, tid);
      __syncthreads();
      gemm_tok<8, 128, true, -1, TRW, 4>(W1, wsb + TWS_W10, b1, 512,
                                         S.xbuf, XS, S.qh, HS, W, lane, wid, NW, S.vT);
      __syncthreads();
      // W2: T=4 -> 16 balanced items (R10 win), 8-wide tiles
      gemm_tok<4, 512, false, -1, TRW, 8>(W2, wsb + TWS_W20, b2, 128,
                                          S.qh, HS, S.obuf, XS, W, lane, wid, NW, S.vT);
      __syncthreads();
      ln_rows(S.xbuf, S.obuf, ln2g, ln2b, W, tid);
      __syncthreads();
      // ---------------- layer 1 (last-token only) ----------------
      {
        const WT* Wq = Wqkv + 384 * 128;
        const WT* bq = bqkv + 384;
        if (wid < 14) {
          gemm_tok<8, 128, false, 128, TRW, 4>(Wq + 128 * 128, wsb + TWS_QKV1, bq + 128, 256,
                                               S.xbuf, XS, S.qh + 128, QS, W, lane, wid, 14, S.vT);
        } else {
          int j = tid - 896;  // 0..127
          S.qh[jl * QS + j] = ldw(bq + j) + dotgf<128>(Wq + j * 128, &S.xbuf[jl * XS]);
        }
        __syncthreads();
        // L1 scores on tid<128  ||  catd-emb gather on tid 896..1023
        if (tid < 128) {
          int h = tid >> 5, j = tid & 31;
          float s = -1e30f;
          if (j < W) {
            s = 0.f;
#pragma unroll
            for (int kk = 0; kk < 8; ++kk)
              s += dot4f(*(const float4*)&S.qh[jl * QS + h * 32 + kk * 4],
                         *(const float4*)&S.qh[j * QS + 128 + h * 32 + kk * 4]);
            s *= 0.17677669529663687f;
          }
          float m = s;
          for (int mk = 16; mk; mk >>= 1) m = fmaxf(m, __shfl_xor(m, mk, 32));
          float e = (j < W) ? expf(s - m) : 0.f;
          float sum = e;
          for (int mk = 16; mk; mk >>= 1) sum += __shfl_xor(sum, mk, 32);
          if (j < W) S.pbuf[h * PS + j] = e * (1.0f / sum);
          else       S.pbuf[h * PS + j] = 0.f;
        } else if (tid >= 896) {
          int j = tid - 896;
          int ipc = ip < 0 ? 0 : (ip > 63 ? 63 : ip);
          int nt = P.token_ids[row * 64 + ipc];
          int has_in = (act && (ip < seq)) ? 1 : 0;
          S.catd[j] = has_in ? (double)temb(P.tok_emb, isbEmb, (long long)nt * 128 + j) : 0.0;
        }
        __syncthreads();
        if (tid < 128) {
          int h = tid >> 5;
          const float* prow = &S.pbuf[h * PS];
          const float* vrow = &S.vT[tid * VS];
          float acc = 0.f;
          for (int j4 = 0; j4 < W; j4 += 4) {
            float4 p = *(const float4*)(prow + j4);
            float4 v = *(const float4*)(vrow + j4);
            acc += p.x * v.x + p.y * v.y + p.z * v.z + p.w * v.w;
          }
          S.attT[tid] = acc;
        }
        __syncthreads();
        // Wo tail, widened 4-way k-split
        if (tid < 512) {
          int j = tid >> 2, q = tid & 3;
          float v = dotgf<32>(Wo + 16384 + (size_t)j * 128 + q * 32, S.attT + q * 32);
          v += __shfl_xor(v, 1, 64);
          v += __shfl_xor(v, 2, 64);
          if (q == 0) S.tva[j] = ldw(bo + 128 + j) + v;
        }
        __syncthreads();
        ln_tail(&S.xbuf[jl * XS], S.tva, ln1g + 128, ln1b + 128, tid);
        __syncthreads();
        // W1 tail, widened 2-way k-split (all 1024 threads)
        {
          int j = tid >> 1, h = tid & 1;
          float v = dotgf<64>(W1 + (size_t)(512 + j) * 128 + h * 64, &S.xbuf[jl * XS] + h * 64);
          v += __shfl_xor(v, 1, 64);
          if (h == 0) S.qh[j] = fmaxf(ldw(b1 + 512 + j) + v, 0.f);
        }
        __syncthreads();
        // W2 tail, widened 4-way k-split
        if (tid < 512) {
          int j = tid >> 2, q = tid & 3;
          float v = dotgf<128>(W2 + (size_t)(128 + j) * 512 + q * 128, S.qh + q * 128);
          v += __shfl_xor(v, 1, 64);
          v += __shfl_xor(v, 2, 64);
          if (q == 0) S.tva[j] = ldw(b2 + 128 + j) + v;
        }
        __syncthreads();
        ln_tail(&S.xbuf[jl * XS], S.tva, ln2g + 128, ln2b + 128, tid);
        __syncthreads();
      }
    }

    // ---- stage A: proj->t1 (+ ghl/catd-emb only when encoder skipped) ----
    if (tid < 64) {
      double tv = 0.0;
      if (enc) {
        double v = ldwd(projb + tid) + dotgdx<128>(projW + tid * 128, &S.xbuf[jl * XS]);
        double ss = wredsumd(v * v, 64);
        tv = v / fmax(sqrt(ss), 1e-12);
      }
      S.t1d[tid] = tv;
      S.catd[128 + tid] = tv;
      P.out[(size_t)t * 4096 + row * 64 + tid] = (float)tv;
    } else if (!enc) {
      if (tid >= 128 && tid < 896) {
        if (act) {
          int jj = tid - 128;          // 0..767
          int j = jj >> 1, h = jj & 1; // lane pairs, same wave
          double v = dotgd<64>(gWhh + (size_t)j * 128 + h * 64, S.hsd + h * 64);
          v += __shfl_xor(v, 1, 64);
          if (h == 0) S.ghld[j] = ldwd(gbhh + j) + v;
        }
      } else if (tid >= 896) {
        int j = tid - 896;
        int ipc = ip < 0 ? 0 : (ip > 63 ? 63 : ip);
        int nt = P.token_ids[row * 64 + ipc];
        int has_in = (act && (ip < seq)) ? 1 : 0;
        S.catd[j] = has_in ? (double)temb(P.tok_emb, isbEmb, (long long)nt * 128 + j) : 0.0;
      }
    }
    __syncthreads();

    // ---- stage B: gil (needs t1), widened 2-way ----
    if (act) {
      if (tid < 768) {
        int j = tid >> 1, h = tid & 1;
        double v = dotgd<32>(gWih + (size_t)j * 64 + h * 32, S.t1d + h * 32);
        v += __shfl_xor(v, 1, 64);
        if (h == 0) S.gild[j] = ldwd(gbih + j) + v;
      }
      __syncthreads();
    }

    // ---- stage C: hsd update + catd-h ----
    if (tid < 128) {
      if (act) {
        double r = 1.0 / (1.0 + exp(-(S.gild[tid] + S.ghld[tid])));
        double z = 1.0 / (1.0 + exp(-(S.gild[128 + tid] + S.ghld[128 + tid])));
        double n = tanh(S.gild[256 + tid] + r * S.ghld[256 + tid]);
        S.hsd[tid] = (1.0 - z) * n + z * S.hsd[tid];
      }
      S.catd[192 + tid] = S.hsd[tid];
    }
    __syncthreads();

    // ---- stage D: three head hidden layers, widened 2-way k-split ----
    if (tid < 768) {
      int jo = tid >> 1, h = tid & 1;
      double v;
      if (jo < 128) {
        v = dotgd<160>(accW1 + (size_t)jo * 320 + h * 160, S.catd + h * 160);
      } else if (jo < 256) {
        int j = jo - 128;
        v = dotgd<96>(emtW1 + (size_t)j * 192 + h * 96, S.catd + 128 + h * 96);
      } else {
        int j = jo - 256;
        v = dotgd<96>(evtW1 + (size_t)j * 192 + h * 96, S.catd + 128 + h * 96);
      }
      v += __shfl_xor(v, 1, 64);
      if (h == 0) {
        double b = (jo < 128) ? ldwd(accb1 + jo)
                 : (jo < 256 ? ldwd(emtb1 + jo - 128) : ldwd(evtb1 + jo - 256));
        S.hid2d[jo] = fmax(b + v, 0.0);
      }
    }
    __syncthreads();

    // ---- stage E: three logits ----
    {
      int hw = tid >> 6;
      if (hw < 3) {
        int ln = tid & 63;
        const WT* w2 = (hw == 0) ? accW2 : ((hw == 1) ? emtW2 : evtW2);
        const WT* b2p = (hw == 0) ? accb2 : ((hw == 1) ? emtb2 : evtb2);
        double pp = S.hid2d[hw * 128 + ln] * ldwd(w2 + ln)
                  + S.hid2d[hw * 128 + 64 + ln] * ldwd(w2 + 64 + ln);
        pp = wredsumd(pp, 64);
        if (ln == 0) S.logitsd[hw] = pp + ldwd(b2p);
      }
    }
    __syncthreads();

    // ---- stage F: sample (3 lanes in parallel) + state update (lane 0) ----
    if (tid < 64) {
      unsigned k0 = S.keyts[t][0], k1 = S.keyts[t][1];
      int smp_l = 0;
      if (tid < 3) {
        double lgv = S.logitsd[tid];
        unsigned sk0, sk1, r0, r1;
        tfry(k0, k1, 0u, (unsigned)tid, sk0, sk1);
        tfry(sk0, sk1, 0u, (unsigned)row, r0, r1);
        double u = (double)u01(r0 ^ r1);
        double p = 1.0 / (1.0 + exp(-lgv));
        smp_l = (u < p) ? 1 : 0;
        P.out[131072 + (size_t)t * 192 + row * 3 + tid] = (float)logsigd(smp_l ? lgv : -lgv);
        P.out[137216 + (size_t)t * 192 + row * 3 + tid] = smp_l ? 1.0f : 0.0f;
      }
      int sa = __shfl(smp_l, 0, 64);
      int se = __shfl(smp_l, 1, 64);
      int sv = __shfl(smp_l, 2, 64);
      if (tid == 0) {
        int wl2 = wl, ip2 = ip, dn = done;
        int nonempty = (wl2 > 0) && act;
        int has_in = act && (ip2 < seq);
        int a = sa && has_in;
        int e = se && nonempty;
        int v = sv && nonempty;
        int none = act && !(a || e || v);
        a = a || (none && has_in);
        e = e || (none && !has_in && (wl2 > 0));
        int aeff = a && (wl2 < 32);
        int ipc = ip2 < 0 ? 0 : (ip2 > 63 ? 63 : ip2);
        int nt = P.token_ids[row * 64 + ipc];
        if (aeff) { S.win_ids[wl2] = nt; ip2 += 1; wl2 += 1; }
        int emit = e && (wl2 > 0);
        S.sI[4] += emit;
        int veff = v && (wl2 > 0);
        if (veff) {
          int w0 = S.win_ids[0];
#pragma unroll
          for (int i2 = 0; i2 < 31; ++i2) S.win_ids[i2] = S.win_ids[i2 + 1];
          S.win_ids[31] = w0;
          wl2 -= 1;
        }
        if (act && (ip2 >= seq) && (wl2 == 0)) dn = 1;
        S.sI[0] = wl2; S.sI[1] = ip2; S.sI[2] = dn;
      }
    }
    __syncthreads();
  }
  if (tid == 0) P.out[143360 + row] = (float)S.sI[4];
}

template<bool TRW>
__global__ __launch_bounds__(1024, 4) void src_main_kernel_t(KParams P){
  __shared__ __align__(16) Smem S;
  const int row = blockIdx.x;
  const int tid = threadIdx.x;
  const bool isb = (((const unsigned short*)P.ln1g)[0] == (unsigned short)0x3F80);
  if (isb) run_all<unsigned short, TRW>(P, S, row, tid, 1);
  else     run_all<float, TRW>(P, S, row, tid, 0);
}

extern "C" void kernel_launch(void* const* d_in, const int* in_sizes, int n_in,
                              void* d_out, int out_size, void* d_ws, size_t ws_size,
                              hipStream_t stream) {
  KParams P;
  P.token_ids = (const int*)d_in[0];
  P.pad = (const unsigned char*)d_in[1];
  P.tok_emb = d_in[4];  P.pos_emb = d_in[5];
  P.Wqkv = d_in[6];     P.bqkv = d_in[7];
  P.Wo = d_in[8];       P.bo = d_in[9];
  P.ln1g = d_in[10];    P.ln1b = d_in[11];
  P.W1 = d_in[12];      P.b1 = d_in[13];
  P.W2 = d_in[14];      P.b2 = d_in[15];
  P.ln2g = d_in[16];    P.ln2b = d_in[17];
  P.projW = d_in[18];   P.projb = d_in[19];
  P.gWih = d_in[20];    P.gWhh = d_in[21];
  P.gbih = d_in[22];    P.gbhh = d_in[23];
  P.accW1 = d_in[24];   P.accb1 = d_in[25];
  P.accW2 = d_in[26];   P.accb2 = d_in[27];
  P.emtW1 = d_in[28];   P.emtb1 = d_in[29];
  P.emtW2 = d_in[30];   P.emtb2 = d_in[31];
  P.evtW1 = d_in[32];   P.evtb1 = d_in[33];
  P.evtW2 = d_in[34];   P.evtb2 = d_in[35];
  P.wst = d_ws;
  P.out = (float*)d_out;
  const bool tr = (d_ws != nullptr) && (ws_size >= (size_t)TWS_TOTAL * 4);
  if (tr) {
    hipLaunchKernelGGL(transpose_w_kernel, dim3((TWS_NVEC + 255) / 256), dim3(256), 0, stream,
                       P.Wqkv, P.Wo, P.W1, P.W2, P.ln1g, d_ws);
    hipLaunchKernelGGL((src_main_kernel_t<true>), dim3(64), dim3(1024), 0, stream, P);
  } else {
    hipLaunchKernelGGL((src_main_kernel_t<false>), dim3(64), dim3(1024), 0, stream, P);
  }
}

// Round 16
// 3788.918 us; speedup vs baseline: 1.1554x; 1.0351x over previous
//
#include <hip/hip_runtime.h>
#include <hip/hip_bf16.h>

// ShiftReduceCompressor: persistent kernel, 1 block/row (B=64), 1024 threads,
// 32-iteration scan in-kernel. Encoder fp32, sampling tail fp64, exact
// partitionable JAX threefry. Fused tail.
//
// Round 16 = R15 (best 3922us) + 8-wide coalesced tiles for ALL five gemm
// weight blocks (R15 had them only on Wo/W2 and it paid exactly the
// predicted ~5ns/wave-load: -204us). Remaining 2.3K 4-wide loads/iter on
// Wqkv/W1/L1 (T=8) now halve too (-170us predicted). T=8 spill risk
// managed via scalar-xv two-pass inner loop (live ~24-32 regs; R7's spill
// had the divergent-address structure on top). Single tile layout
// [cg][k/8][lane][8]; FMA order ascending k -> bit-identical numerics.
// Spill canary: WRITE jump >= 1.5MB => revert to R15.

#define XS 132
#define QS 388
#define HS 516
#define PS 36
#define VS 36
#define NW 16

// transposed-weight workspace offsets (elements of WT); all blocks 8-wide
#define TWS_QKV0 0        // 384x128
#define TWS_WO0  49152    // 128x128
#define TWS_W10  65536    // 512x128
#define TWS_W20  131072   // 128x512
#define TWS_QKV1 196608   // 256x128 (layer-1 K,V rows)
#define TWS_TOTAL 229376
#define TWS_NVEC (TWS_TOTAL / 4)   // 57344

struct KParams {
  const int* token_ids;
  const unsigned char* pad;
  const void *tok_emb, *pos_emb, *Wqkv, *bqkv, *Wo, *bo, *ln1g, *ln1b;
  const void *W1, *b1, *W2, *b2, *ln2g, *ln2b, *projW, *projb;
  const void *gWih, *gWhh, *gbih, *gbhh;
  const void *accW1, *accb1, *accW2, *accb2;
  const void *emtW1, *emtb1, *emtW2, *emtb2;
  const void *evtW1, *evtb1, *evtW2, *evtb2;
  const void *wst;   // transposed weights (d_ws) or null
  float* out;
};

struct Smem {
  float xbuf[32 * XS];
  float qh[32 * HS];
  float obuf[32 * XS];
  float pbuf[4608];
  float vT[128 * VS];
  float attT[128];
  float tva[128];
  double gild[384];
  double ghld[384];
  double hsd[128];
  double t1d[64];
  double catd[320];
  double hid2d[384];
  double logitsd[3];
  int win_ids[32];
  int sI[6];
  unsigned keyts[32][2];
};

// ---------- typed loads (f32 or bf16) ----------
__device__ __forceinline__ float ldw(const float* p){ return *p; }
__device__ __forceinline__ float ldw(const unsigned short* p){
  return __uint_as_float(((unsigned)*p) << 16);
}
__device__ __forceinline__ float4 ld4(const float* p){ return *(const float4*)p; }
__device__ __forceinline__ float4 ld4(const unsigned short* p){
  ushort4 u = *(const ushort4*)p;
  return make_float4(__uint_as_float((unsigned)u.x << 16),
                     __uint_as_float((unsigned)u.y << 16),
                     __uint_as_float((unsigned)u.z << 16),
                     __uint_as_float((unsigned)u.w << 16));
}
// 8 consecutive elems in one shot (bf16: one 16B uint4 + unpack; f32: two float4)
__device__ __forceinline__ void ld8(const float* p, float4& a, float4& b){
  a = *(const float4*)p; b = *(const float4*)(p + 4);
}
__device__ __forceinline__ void ld8(const unsigned short* p, float4& a, float4& b){
  uint4 u = *(const uint4*)p;
  a.x = __uint_as_float(u.x << 16); a.y = __uint_as_float(u.x & 0xffff0000u);
  a.z = __uint_as_float(u.y << 16); a.w = __uint_as_float(u.y & 0xffff0000u);
  b.x = __uint_as_float(u.z << 16); b.y = __uint_as_float(u.z & 0xffff0000u);
  b.z = __uint_as_float(u.w << 16); b.w = __uint_as_float(u.w & 0xffff0000u);
}
template<typename WT>
__device__ __forceinline__ double ldwd(const WT* p){ return (double)ldw(p); }

__device__ __forceinline__ float temb(const void* te, int isb, long long idx){
  if (isb) return __uint_as_float(((unsigned)((const unsigned short*)te)[idx]) << 16);
  return ((const float*)te)[idx];
}

// ---------- JAX threefry2x32 (partitionable) ----------
__device__ __forceinline__ void tfry(unsigned k0, unsigned k1, unsigned x0, unsigned x1,
                                     unsigned &o0, unsigned &o1){
  unsigned ks2 = k0 ^ k1 ^ 0x1BD11BDAu;
  unsigned x = x0 + k0, y = x1 + k1;
#define TFR(r) { x += y; y = (y << r) | (y >> (32 - r)); y ^= x; }
  TFR(13) TFR(15) TFR(26) TFR(6)  x += k1;  y += ks2 + 1u;
  TFR(17) TFR(29) TFR(16) TFR(24) x += ks2; y += k0 + 2u;
  TFR(13) TFR(15) TFR(26) TFR(6)  x += k0;  y += k1 + 3u;
  TFR(17) TFR(29) TFR(16) TFR(24) x += k1;  y += ks2 + 4u;
  TFR(13) TFR(15) TFR(26) TFR(6)  x += ks2; y += k0 + 5u;
#undef TFR
  o0 = x; o1 = y;
}
__device__ __forceinline__ float u01(unsigned bits){
  return __uint_as_float((bits >> 9) | 0x3f800000u) - 1.0f;
}
__device__ __forceinline__ double logsigd(double x){
  return fmin(x, 0.0) - log1p(exp(-fabs(x)));
}
__device__ __forceinline__ float wredsum(float v, int width){
  for (int m = width >> 1; m > 0; m >>= 1) v += __shfl_xor(v, m, width);
  return v;
}
__device__ __forceinline__ double wredsumd(double v, int width){
  for (int m = width >> 1; m > 0; m >>= 1) v += __shfl_xor(v, m, width);
  return v;
}
__device__ __forceinline__ float dot4f(float4 a, float4 b){
  return a.x*b.x + a.y*b.y + a.z*b.z + a.w*b.w;
}

// ---------- weight transpose pre-pass (all blocks 8-wide) ----------
// dst elems ((cg*(K/8)+k8)*64+lane)*8 + e4*4 hold
//   W[(cg*64+lane)*K + k8*8 + e4*4 ..+3]. One thread per 4-elem vector.
__global__ __launch_bounds__(256) void transpose_w_kernel(
    const void* Wqkv, const void* Wo, const void* W1, const void* W2,
    const void* ln1g, void* ws)
{
  const bool isb = (((const unsigned short*)ln1g)[0] == (unsigned short)0x3F80);
  int i = blockIdx.x * 256 + threadIdx.x;
  if (i >= TWS_NVEC) return;
  const void* src; int K4; long long srcBase = 0; int dstBase; int local;
  if (i < 12288)      { src = Wqkv; K4 = 32;  local = i;         dstBase = TWS_QKV0; }
  else if (i < 16384) { src = Wo;   K4 = 32;  local = i - 12288; dstBase = TWS_WO0; }
  else if (i < 32768) { src = W1;   K4 = 32;  local = i - 16384; dstBase = TWS_W10; }
  else if (i < 49152) { src = W2;   K4 = 128; local = i - 32768; dstBase = TWS_W20; }
  else                { src = Wqkv; K4 = 32;  local = i - 49152; srcBase = 384*128+128*128; dstBase = TWS_QKV1; }
  const int K8 = K4 >> 1;
  const int e4 = local & 1, r = local >> 1;
  const int lane = r & 63, k8 = (r >> 6) % K8, cg = r / (64 * K8);
  const long long srcElem = srcBase + (long long)(cg * 64 + lane) * (K4 * 4) + (long long)k8 * 8 + e4 * 4;
  const long long dstElem = (long long)dstBase + ((long long)((cg * K8 + k8) * 64 + lane)) * 8 + e4 * 4;
  if (isb) ((uint2*)ws)[dstElem >> 2] = ((const uint2*)src)[srcElem >> 2];
  else     ((uint4*)ws)[dstElem >> 2] = ((const uint4*)src)[srcElem >> 2];
}

// out[tok][j] = bias[j] + sum_k W[j][k]*x[tok][k]; lane=j mod 64,
// T tokens share one 8-wide weight fetch per k8-step (coalesced 1KB/wave
// from the lane-major tile). Scalar-xv two-pass inner loop keeps the live
// set ~24-32 regs for any T. FMA order ascending k -> bit-identical.
// If VOFF >= 0, columns j0 >= VOFF are V columns -> vt transposed.
template<int T, int K, bool RELU, int VOFF, bool TRW, typename WT>
__device__ void gemm_tok(const WT* __restrict__ Wm, const WT* __restrict__ Wt,
                         const WT* __restrict__ bias,
                         int J, const float* __restrict__ xl, int xs,
                         float* __restrict__ ol, int os, int ntok,
                         int lane, int wv, int nwv, float* __restrict__ vt)
{
  const int JBG = J >> 6;
  const int ntt = (ntok + T - 1) / T;
  for (int item = wv; item < JBG * ntt; item += nwv) {
    const int jg = item % JBG, tt = item / JBG;
    const int j0 = jg * 64 + lane;
    float acc[T];
#pragma unroll
    for (int t = 0; t < T; ++t) acc[t] = 0.f;
    const float* xr = xl + tt * T * xs;
    const WT* wr0 = TRW ? (Wt + ((size_t)jg * (K / 8) * 64 + lane) * 8)
                        : (Wm + (size_t)j0 * K);
    const WT* wrp = wr0;
#pragma unroll 2
    for (int k = 0; k < K; k += 8) {
      float4 wA, wB;
      if (TRW) { ld8(wrp, wA, wB); wrp += 512; }
      else     { wA = ld4(wr0 + k); wB = ld4(wr0 + k + 4); }
#pragma unroll
      for (int t = 0; t < T; ++t) {
        float4 xv = *(const float4*)(xr + t * xs + k);
        acc[t] += wA.x * xv.x + wA.y * xv.y + wA.z * xv.z + wA.w * xv.w;
      }
#pragma unroll
      for (int t = 0; t < T; ++t) {
        float4 xv = *(const float4*)(xr + t * xs + k + 4);
        acc[t] += wB.x * xv.x + wB.y * xv.y + wB.z * xv.z + wB.w * xv.w;
      }
    }
    float bj = ldw(bias + j0);
#pragma unroll
    for (int t = 0; t < T; ++t) {
      int tok = tt * T + t;
      if (tok < ntok) {
        float v = acc[t] + bj;
        if (RELU) v = fmaxf(v, 0.f);
        if (VOFF >= 0 && j0 >= VOFF) vt[(j0 - VOFF) * VS + tok] = v;
        else                         ol[tok * os + j0] = v;
      }
    }
  }
}

template<int K, typename WT>
__device__ __forceinline__ float dotgf(const WT* __restrict__ w, const float* x){
  float acc = 0.f;
#pragma unroll 8
  for (int k = 0; k < K; k += 4) {
    float4 wv = ld4(w + k);
    acc += wv.x * x[k] + wv.y * x[k+1] + wv.z * x[k+2] + wv.w * x[k+3];
  }
  return acc;
}
template<int K, typename WT>
__device__ __forceinline__ double dotgd(const WT* __restrict__ w, const double* x){
  double acc = 0.0;
#pragma unroll 8
  for (int k = 0; k < K; k += 4) {
    float4 wv = ld4(w + k);
    acc += (double)wv.x * x[k] + (double)wv.y * x[k+1]
         + (double)wv.z * x[k+2] + (double)wv.w * x[k+3];
  }
  return acc;
}
template<int K, typename WT>
__device__ __forceinline__ double dotgdx(const WT* __restrict__ w, const float* x){
  double acc = 0.0;
#pragma unroll 8
  for (int k = 0; k < K; k += 4) {
    float4 wv = ld4(w + k);
    acc += (double)wv.x * (double)x[k] + (double)wv.y * (double)x[k+1]
         + (double)wv.z * (double)x[k+2] + (double)wv.w * (double)x[k+3];
  }
  return acc;
}

template<typename WT>
__device__ void ln_rows(float* xb, const float* ob, const WT* __restrict__ g,
                        const WT* __restrict__ bb, int W, int tid){
  if (tid >= 256) return;
  const int i = tid >> 3, sub = tid & 7;
  const int base = i * XS + sub * 16;
  float y[16];
  float s = 0.f;
#pragma unroll
  for (int u = 0; u < 16; u += 4) {
    float4 xv = *(const float4*)(xb + base + u);
    float4 ov = *(const float4*)(ob + base + u);
    y[u] = xv.x + ov.x; y[u+1] = xv.y + ov.y; y[u+2] = xv.z + ov.z; y[u+3] = xv.w + ov.w;
    s += y[u] + y[u+1] + y[u+2] + y[u+3];
  }
  s = wredsum(s, 8);
  const float m = s * (1.0f / 128.0f);
  float vs = 0.f;
#pragma unroll
  for (int u = 0; u < 16; ++u) { float d = y[u] - m; vs += d * d; }
  vs = wredsum(vs, 8);
  const float rstd = 1.0f / sqrtf(vs * (1.0f / 128.0f) + 1e-5f);
  if (i < W) {
#pragma unroll
    for (int u = 0; u < 16; u += 4) {
      float4 gg = ld4(g + sub * 16 + u);
      float4 bv = ld4(bb + sub * 16 + u);
      float4 r;
      r.x = (y[u]   - m) * rstd * gg.x + bv.x;
      r.y = (y[u+1] - m) * rstd * gg.y + bv.y;
      r.z = (y[u+2] - m) * rstd * gg.z + bv.z;
      r.w = (y[u+3] - m) * rstd * gg.w + bv.w;
      *(float4*)(xb + base + u) = r;
    }
  }
}
template<typename WT>
__device__ __forceinline__ void ln_tail(float* xrow, const float* add,
                                        const WT* __restrict__ g,
                                        const WT* __restrict__ bb, int tid){
  if (tid < 64) {
    float y0 = xrow[tid] + add[tid];
    float y1 = xrow[64 + tid] + add[64 + tid];
    float m = wredsum(y0 + y1, 64) * (1.0f / 128.0f);
    float d0 = y0 - m, d1 = y1 - m;
    float rstd = 1.0f / sqrtf(wredsum(d0 * d0 + d1 * d1, 64) * (1.0f / 128.0f) + 1e-5f);
    xrow[tid] = d0 * rstd * ldw(g + tid) + ldw(bb + tid);
    xrow[64 + tid] = d1 * rstd * ldw(g + 64 + tid) + ldw(bb + 64 + tid);
  }
}

template<typename WT, bool TRW>
__device__ void run_all(const KParams& P, Smem& S, int row, int tid, int isbEmb){
  const WT* tok_embw = (const WT*)P.tok_emb;
  const WT* pos_emb = (const WT*)P.pos_emb;
  const WT* Wqkv = (const WT*)P.Wqkv;   const WT* bqkv = (const WT*)P.bqkv;
  const WT* Wo = (const WT*)P.Wo;       const WT* bo = (const WT*)P.bo;
  const WT* ln1g = (const WT*)P.ln1g;   const WT* ln1b = (const WT*)P.ln1b;
  const WT* W1 = (const WT*)P.W1;       const WT* b1 = (const WT*)P.b1;
  const WT* W2 = (const WT*)P.W2;       const WT* b2 = (const WT*)P.b2;
  const WT* ln2g = (const WT*)P.ln2g;   const WT* ln2b = (const WT*)P.ln2b;
  const WT* projW = (const WT*)P.projW; const WT* projb = (const WT*)P.projb;
  const WT* gWih = (const WT*)P.gWih;   const WT* gWhh = (const WT*)P.gWhh;
  const WT* gbih = (const WT*)P.gbih;   const WT* gbhh = (const WT*)P.gbhh;
  const WT* accW1 = (const WT*)P.accW1; const WT* accb1 = (const WT*)P.accb1;
  const WT* accW2 = (const WT*)P.accW2; const WT* accb2 = (const WT*)P.accb2;
  const WT* emtW1 = (const WT*)P.emtW1; const WT* emtb1 = (const WT*)P.emtb1;
  const WT* emtW2 = (const WT*)P.emtW2; const WT* emtb2 = (const WT*)P.emtb2;
  const WT* evtW1 = (const WT*)P.evtW1; const WT* evtb1 = (const WT*)P.evtb1;
  const WT* evtW2 = (const WT*)P.evtW2; const WT* evtb2 = (const WT*)P.evtb2;
  const WT* wsb = (const WT*)P.wst;

  const int lane = tid & 63, wid = tid >> 6;

  if (tid == 0) {
    int seq = 0;
    for (int l = 0; l < 64; ++l) seq += (P.pad[row * 64 + l] == 0);
    S.sI[0] = 0; S.sI[1] = 0; S.sI[2] = (seq == 0) ? 1 : 0; S.sI[3] = seq; S.sI[4] = 0;
  }
  if (tid < 128) S.hsd[tid] = 0.0;
  if (tid < 32) {
    S.win_ids[tid] = 0;
    unsigned a0, a1;
    tfry(0u, 42u, 0u, (unsigned)tid, a0, a1);
    S.keyts[tid][0] = a0; S.keyts[tid][1] = a1;
  }
  for (int idx = tid; idx < 128 * VS; idx += 1024) S.vT[idx] = 0.f;
  __syncthreads();

  for (int t = 0; t < 32; ++t) {
    const int wl = S.sI[0], ip = S.sI[1], done = S.sI[2], seq = S.sI[3];
    const int act = !done;
    const int W = wl;
    const int enc = (act && wl > 0) ? 1 : 0;
    const int jl = (W > 0) ? (W - 1) : 0;
    const int Wp4 = (W + 3) & ~3;

    if (enc) {
      // embedding fill, 8 elems/thread, vectorized
      for (int idx = tid; idx < W * 16; idx += 1024) {
        int i = idx >> 4, d0 = (idx & 15) << 3;
        const WT* te = tok_embw + (long long)S.win_ids[i] * 128 + d0;
        const WT* pe = pos_emb + (size_t)i * 128 + d0;
        float4 t0 = ld4(te), t1 = ld4(te + 4), p0 = ld4(pe), p1 = ld4(pe + 4);
        float* dst = &S.xbuf[i * XS + d0];
        float4 r0, r1;
        r0.x = t0.x + p0.x; r0.y = t0.y + p0.y; r0.z = t0.z + p0.z; r0.w = t0.w + p0.w;
        r1.x = t1.x + p1.x; r1.y = t1.y + p1.y; r1.z = t1.z + p1.z; r1.w = t1.w + p1.w;
        *(float4*)dst = r0;
        *(float4*)(dst + 4) = r1;
      }
      __syncthreads();
      // ---------------- layer 0 (full) ----------------
      gemm_tok<8, 128, false, 256, TRW>(Wqkv, wsb + TWS_QKV0, bqkv, 384,
                                        S.xbuf, XS, S.qh, QS, W, lane, wid, NW, S.vT);
      __syncthreads();
      // scores+softmax on tid<256  ||  GRU ghl (prev-iter hsd) on tid 256..1023
      if (tid < 256) {
        int r = tid >> 1, half = tid & 1;
        int h = r >> 5, i = r & 31;
        if (i < W) {
          float4 q[8];
#pragma unroll
          for (int kk = 0; kk < 8; ++kk) q[kk] = *(const float4*)&S.qh[i * QS + h * 32 + kk * 4];
          const int pb = r * PS;
          const int j0 = half * 16;
          const int j1 = (j0 + 16 < W) ? (j0 + 16) : W;
          float m = -1e30f;
          for (int j = j0; j < j1; ++j) {
            float s = 0.f;
#pragma unroll
            for (int kk = 0; kk < 8; ++kk)
              s += dot4f(q[kk], *(const float4*)&S.qh[j * QS + 128 + h * 32 + kk * 4]);
            s *= 0.17677669529663687f;
            S.pbuf[pb + j] = s;
            m = fmaxf(m, s);
          }
          m = fmaxf(m, __shfl_xor(m, 1, 64));
          float sum = 0.f;
          for (int j = j0; j < j1; ++j) {
            float e = expf(S.pbuf[pb + j] - m);
            S.pbuf[pb + j] = e;
            sum += e;
          }
          sum += __shfl_xor(sum, 1, 64);
          float rs = 1.0f / sum;
          for (int j = j0; j < j1; ++j) S.pbuf[pb + j] *= rs;
          for (int j = W + half; j < Wp4; j += 2) S.pbuf[pb + j] = 0.f;
        }
      } else if (act) {
        int jj = tid - 256;          // 0..767
        int j = jj >> 1, h = jj & 1; // lane pairs, same wave
        double v = dotgd<64>(gWhh + (size_t)j * 128 + h * 64, S.hsd + h * 64);
        v += __shfl_xor(v, 1, 64);
        if (h == 0) S.ghld[j] = ldwd(gbhh + j) + v;
      }
      __syncthreads();
      // AV via transposed V: float4 over j for probs and V
      {
        int c = tid & 127, g = tid >> 7;
        int h = c >> 5;
        const float* vrow = &S.vT[c * VS];
        for (int i = g; i < W; i += 8) {
          const float* prow = &S.pbuf[(h * 32 + i) * PS];
          float acc = 0.f;
          for (int j4 = 0; j4 < W; j4 += 4) {
            float4 p = *(const float4*)(prow + j4);
            float4 v = *(const float4*)(vrow + j4);
            acc += p.x * v.x + p.y * v.y + p.z * v.z + p.w * v.w;
          }
          S.obuf[i * XS + c] = acc;
        }
      }
      __syncthreads();
      gemm_tok<4, 128, false, -1, TRW>(Wo, wsb + TWS_WO0, bo, 128,
                                       S.obuf, XS, S.pbuf, XS, W, lane, wid, NW, S.vT);
      __syncthreads();
      ln_rows(S.xbuf, S.pbuf, ln1g, ln1b, W, tid);
      __syncthreads();
      gemm_tok<8, 128, true, -1, TRW>(W1, wsb + TWS_W10, b1, 512,
                                      S.xbuf, XS, S.qh, HS, W, lane, wid, NW, S.vT);
      __syncthreads();
      // W2: T=4 -> 16 balanced items (R10 win)
      gemm_tok<4, 512, false, -1, TRW>(W2, wsb + TWS_W20, b2, 128,
                                       S.qh, HS, S.obuf, XS, W, lane, wid, NW, S.vT);
      __syncthreads();
      ln_rows(S.xbuf, S.obuf, ln2g, ln2b, W, tid);
      __syncthreads();
      // ---------------- layer 1 (last-token only) ----------------
      {
        const WT* Wq = Wqkv + 384 * 128;
        const WT* bq = bqkv + 384;
        if (wid < 14) {
          gemm_tok<8, 128, false, 128, TRW>(Wq + 128 * 128, wsb + TWS_QKV1, bq + 128, 256,
                                            S.xbuf, XS, S.qh + 128, QS, W, lane, wid, 14, S.vT);
        } else {
          int j = tid - 896;  // 0..127
          S.qh[jl * QS + j] = ldw(bq + j) + dotgf<128>(Wq + j * 128, &S.xbuf[jl * XS]);
        }
        __syncthreads();
        // L1 scores on tid<128  ||  catd-emb gather on tid 896..1023
        if (tid < 128) {
          int h = tid >> 5, j = tid & 31;
          float s = -1e30f;
          if (j < W) {
            s = 0.f;
#pragma unroll
            for (int kk = 0; kk < 8; ++kk)
              s += dot4f(*(const float4*)&S.qh[jl * QS + h * 32 + kk * 4],
                         *(const float4*)&S.qh[j * QS + 128 + h * 32 + kk * 4]);
            s *= 0.17677669529663687f;
          }
          float m = s;
          for (int mk = 16; mk; mk >>= 1) m = fmaxf(m, __shfl_xor(m, mk, 32));
          float e = (j < W) ? expf(s - m) : 0.f;
          float sum = e;
          for (int mk = 16; mk; mk >>= 1) sum += __shfl_xor(sum, mk, 32);
          if (j < W) S.pbuf[h * PS + j] = e * (1.0f / sum);
          else       S.pbuf[h * PS + j] = 0.f;
        } else if (tid >= 896) {
          int j = tid - 896;
          int ipc = ip < 0 ? 0 : (ip > 63 ? 63 : ip);
          int nt = P.token_ids[row * 64 + ipc];
          int has_in = (act && (ip < seq)) ? 1 : 0;
          S.catd[j] = has_in ? (double)temb(P.tok_emb, isbEmb, (long long)nt * 128 + j) : 0.0;
        }
        __syncthreads();
        if (tid < 128) {
          int h = tid >> 5;
          const float* prow = &S.pbuf[h * PS];
          const float* vrow = &S.vT[tid * VS];
          float acc = 0.f;
          for (int j4 = 0; j4 < W; j4 += 4) {
            float4 p = *(const float4*)(prow + j4);
            float4 v = *(const float4*)(vrow + j4);
            acc += p.x * v.x + p.y * v.y + p.z * v.z + p.w * v.w;
          }
          S.attT[tid] = acc;
        }
        __syncthreads();
        // Wo tail, widened 4-way k-split
        if (tid < 512) {
          int j = tid >> 2, q = tid & 3;
          float v = dotgf<32>(Wo + 16384 + (size_t)j * 128 + q * 32, S.attT + q * 32);
          v += __shfl_xor(v, 1, 64);
          v += __shfl_xor(v, 2, 64);
          if (q == 0) S.tva[j] = ldw(bo + 128 + j) + v;
        }
        __syncthreads();
        ln_tail(&S.xbuf[jl * XS], S.tva, ln1g + 128, ln1b + 128, tid);
        __syncthreads();
        // W1 tail, widened 2-way k-split (all 1024 threads)
        {
          int j = tid >> 1, h = tid & 1;
          float v = dotgf<64>(W1 + (size_t)(512 + j) * 128 + h * 64, &S.xbuf[jl * XS] + h * 64);
          v += __shfl_xor(v, 1, 64);
          if (h == 0) S.qh[j] = fmaxf(ldw(b1 + 512 + j) + v, 0.f);
        }
        __syncthreads();
        // W2 tail, widened 4-way k-split
        if (tid < 512) {
          int j = tid >> 2, q = tid & 3;
          float v = dotgf<128>(W2 + (size_t)(128 + j) * 512 + q * 128, S.qh + q * 128);
          v += __shfl_xor(v, 1, 64);
          v += __shfl_xor(v, 2, 64);
          if (q == 0) S.tva[j] = ldw(b2 + 128 + j) + v;
        }
        __syncthreads();
        ln_tail(&S.xbuf[jl * XS], S.tva, ln2g + 128, ln2b + 128, tid);
        __syncthreads();
      }
    }

    // ---- stage A: proj->t1 (+ ghl/catd-emb only when encoder skipped) ----
    if (tid < 64) {
      double tv = 0.0;
      if (enc) {
        double v = ldwd(projb + tid) + dotgdx<128>(projW + tid * 128, &S.xbuf[jl * XS]);
        double ss = wredsumd(v * v, 64);
        tv = v / fmax(sqrt(ss), 1e-12);
      }
      S.t1d[tid] = tv;
      S.catd[128 + tid] = tv;
      P.out[(size_t)t * 4096 + row * 64 + tid] = (float)tv;
    } else if (!enc) {
      if (tid >= 128 && tid < 896) {
        if (act) {
          int jj = tid - 128;          // 0..767
          int j = jj >> 1, h = jj & 1; // lane pairs, same wave
          double v = dotgd<64>(gWhh + (size_t)j * 128 + h * 64, S.hsd + h * 64);
          v += __shfl_xor(v, 1, 64);
          if (h == 0) S.ghld[j] = ldwd(gbhh + j) + v;
        }
      } else if (tid >= 896) {
        int j = tid - 896;
        int ipc = ip < 0 ? 0 : (ip > 63 ? 63 : ip);
        int nt = P.token_ids[row * 64 + ipc];
        int has_in = (act && (ip < seq)) ? 1 : 0;
        S.catd[j] = has_in ? (double)temb(P.tok_emb, isbEmb, (long long)nt * 128 + j) : 0.0;
      }
    }
    __syncthreads();

    // ---- stage B: gil (needs t1), widened 2-way ----
    if (act) {
      if (tid < 768) {
        int j = tid >> 1, h = tid & 1;
        double v = dotgd<32>(gWih + (size_t)j * 64 + h * 32, S.t1d + h * 32);
        v += __shfl_xor(v, 1, 64);
        if (h == 0) S.gild[j] = ldwd(gbih + j) + v;
      }
      __syncthreads();
    }

    // ---- stage C: hsd update + catd-h ----
    if (tid < 128) {
      if (act) {
        double r = 1.0 / (1.0 + exp(-(S.gild[tid] + S.ghld[tid])));
        double z = 1.0 / (1.0 + exp(-(S.gild[128 + tid] + S.ghld[128 + tid])));
        double n = tanh(S.gild[256 + tid] + r * S.ghld[256 + tid]);
        S.hsd[tid] = (1.0 - z) * n + z * S.hsd[tid];
      }
      S.catd[192 + tid] = S.hsd[tid];
    }
    __syncthreads();

    // ---- stage D: three head hidden layers, widened 2-way k-split ----
    if (tid < 768) {
      int jo = tid >> 1, h = tid & 1;
      double v;
      if (jo < 128) {
        v = dotgd<160>(accW1 + (size_t)jo * 320 + h * 160, S.catd + h * 160);
      } else if (jo < 256) {
        int j = jo - 128;
        v = dotgd<96>(emtW1 + (size_t)j * 192 + h * 96, S.catd + 128 + h * 96);
      } else {
        int j = jo - 256;
        v = dotgd<96>(evtW1 + (size_t)j * 192 + h * 96, S.catd + 128 + h * 96);
      }
      v += __shfl_xor(v, 1, 64);
      if (h == 0) {
        double b = (jo < 128) ? ldwd(accb1 + jo)
                 : (jo < 256 ? ldwd(emtb1 + jo - 128) : ldwd(evtb1 + jo - 256));
        S.hid2d[jo] = fmax(b + v, 0.0);
      }
    }
    __syncthreads();

    // ---- stage E: three logits ----
    {
      int hw = tid >> 6;
      if (hw < 3) {
        int ln = tid & 63;
        const WT* w2 = (hw == 0) ? accW2 : ((hw == 1) ? emtW2 : evtW2);
        const WT* b2p = (hw == 0) ? accb2 : ((hw == 1) ? emtb2 : evtb2);
        double pp = S.hid2d[hw * 128 + ln] * ldwd(w2 + ln)
                  + S.hid2d[hw * 128 + 64 + ln] * ldwd(w2 + 64 + ln);
        pp = wredsumd(pp, 64);
        if (ln == 0) S.logitsd[hw] = pp + ldwd(b2p);
      }
    }
    __syncthreads();

    // ---- stage F: sample (3 lanes in parallel) + state update (lane 0) ----
    if (tid < 64) {
      unsigned k0 = S.keyts[t][0], k1 = S.keyts[t][1];
      int smp_l = 0;
      if (tid < 3) {
        double lgv = S.logitsd[tid];
        unsigned sk0, sk1, r0, r1;
        tfry(k0, k1, 0u, (unsigned)tid, sk0, sk1);
        tfry(sk0, sk1, 0u, (unsigned)row, r0, r1);
        double u = (double)u01(r0 ^ r1);
        double p = 1.0 / (1.0 + exp(-lgv));
        smp_l = (u < p) ? 1 : 0;
        P.out[131072 + (size_t)t * 192 + row * 3 + tid] = (float)logsigd(smp_l ? lgv : -lgv);
        P.out[137216 + (size_t)t * 192 + row * 3 + tid] = smp_l ? 1.0f : 0.0f;
      }
      int sa = __shfl(smp_l, 0, 64);
      int se = __shfl(smp_l, 1, 64);
      int sv = __shfl(smp_l, 2, 64);
      if (tid == 0) {
        int wl2 = wl, ip2 = ip, dn = done;
        int nonempty = (wl2 > 0) && act;
        int has_in = act && (ip2 < seq);
        int a = sa && has_in;
        int e = se && nonempty;
        int v = sv && nonempty;
        int none = act && !(a || e || v);
        a = a || (none && has_in);
        e = e || (none && !has_in && (wl2 > 0));
        int aeff = a && (wl2 < 32);
        int ipc = ip2 < 0 ? 0 : (ip2 > 63 ? 63 : ip2);
        int nt = P.token_ids[row * 64 + ipc];
        if (aeff) { S.win_ids[wl2] = nt; ip2 += 1; wl2 += 1; }
        int emit = e && (wl2 > 0);
        S.sI[4] += emit;
        int veff = v && (wl2 > 0);
        if (veff) {
          int w0 = S.win_ids[0];
#pragma unroll
          for (int i2 = 0; i2 < 31; ++i2) S.win_ids[i2] = S.win_ids[i2 + 1];
          S.win_ids[31] = w0;
          wl2 -= 1;
        }
        if (act && (ip2 >= seq) && (wl2 == 0)) dn = 1;
        S.sI[0] = wl2; S.sI[1] = ip2; S.sI[2] = dn;
      }
    }
    __syncthreads();
  }
  if (tid == 0) P.out[143360 + row] = (float)S.sI[4];
}

template<bool TRW>
__global__ __launch_bounds__(1024, 4) void src_main_kernel_t(KParams P){
  __shared__ __align__(16) Smem S;
  const int row = blockIdx.x;
  const int tid = threadIdx.x;
  const bool isb = (((const unsigned short*)P.ln1g)[0] == (unsigned short)0x3F80);
  if (isb) run_all<unsigned short, TRW>(P, S, row, tid, 1);
  else     run_all<float, TRW>(P, S, row, tid, 0);
}

extern "C" void kernel_launch(void* const* d_in, const int* in_sizes, int n_in,
                              void* d_out, int out_size, void* d_ws, size_t ws_size,
                              hipStream_t stream) {
  KParams P;
  P.token_ids = (const int*)d_in[0];
  P.pad = (const unsigned char*)d_in[1];
  P.tok_emb = d_in[4];  P.pos_emb = d_in[5];
  P.Wqkv = d_in[6];     P.bqkv = d_in[7];
  P.Wo = d_in[8];       P.bo = d_in[9];
  P.ln1g = d_in[10];    P.ln1b = d_in[11];
  P.W1 = d_in[12];      P.b1 = d_in[13];
  P.W2 = d_in[14];      P.b2 = d_in[15];
  P.ln2g = d_in[16];    P.ln2b = d_in[17];
  P.projW = d_in[18];   P.projb = d_in[19];
  P.gWih = d_in[20];    P.gWhh = d_in[21];
  P.gbih = d_in[22];    P.gbhh = d_in[23];
  P.accW1 = d_in[24];   P.accb1 = d_in[25];
  P.accW2 = d_in[26];   P.accb2 = d_in[27];
  P.emtW1 = d_in[28];   P.emtb1 = d_in[29];
  P.emtW2 = d_in[30];   P.emtb2 = d_in[31];
  P.evtW1 = d_in[32];   P.evtb1 = d_in[33];
  P.evtW2 = d_in[34];   P.evtb2 = d_in[35];
  P.wst = d_ws;
  P.out = (float*)d_out;
  const bool tr = (d_ws != nullptr) && (ws_size >= (size_t)TWS_TOTAL * 4);
  if (tr) {
    hipLaunchKernelGGL(transpose_w_kernel, dim3((TWS_NVEC + 255) / 256), dim3(256), 0, stream,
                       P.Wqkv, P.Wo, P.W1, P.W2, P.ln1g, d_ws);
    hipLaunchKernelGGL((src_main_kernel_t<true>), dim3(64), dim3(1024), 0, stream, P);
  } else {
    hipLaunchKernelGGL((src_main_kernel_t<false>), dim3(64), dim3(1024), 0, stream, P);
  }
}